// Round 9
// baseline (400.844 us; speedup 1.0000x reference)
//
#include <hip/hip_runtime.h>

#define B_   32
#define NT_  1002
#define D_   128
#define H_   8
#define FF_  512
#define ROWS (B_ * NT_)          // 32064 = 501*64
#define NEGV (-1e9f)
#define NTP  1024                // padded rows per (b,head)

typedef __bf16 bf16;
typedef __bf16 bf16x8 __attribute__((ext_vector_type(8)));
typedef __bf16 bf16x4 __attribute__((ext_vector_type(4)));
typedef float  f32x4  __attribute__((ext_vector_type(4)));
typedef float  f32x16 __attribute__((ext_vector_type(16)));

#if __has_builtin(__builtin_amdgcn_exp2f)
#define EXP2(x) __builtin_amdgcn_exp2f(x)
#else
#define EXP2(x) exp2f(x)
#endif

#define MFMA16(a, b, c) __builtin_amdgcn_mfma_f32_16x16x32_bf16(a, b, c, 0, 0, 0)

// XOR-swizzled unit-linear LDS addressing for 64x128 A-tiles:
// 16B unit for (row, seg) with seg = k/8.  Staging (row fixed, seg varies) and
// fragment reads (16 lanes = 16 rows, seg fixed) are both conflict-free.
__device__ __forceinline__ int UNITX(int row, int seg) {
  return (row >> 4) * 256 + seg * 16 + ((row & 15) ^ seg);
}

// ---------------- weight prep: transpose + convert to bf16 [n][k] ----------------
#define SZ_QKV (2*384*128)
#define SZ_WO  (2*128*128)
#define SZ_W1  (2*512*128)
#define SZ_W2  (2*128*512)
#define SZ_PROJ (384*128)

__global__ __launch_bounds__(256) void prep_w(
    const float* __restrict__ qkv, const float* __restrict__ wo, const float* __restrict__ w1,
    const float* __restrict__ w2, const float* __restrict__ proj, bf16* __restrict__ out) {
  int i = blockIdx.x * 256 + threadIdx.x;
  int j = i;
  float v;
  if (j < SZ_QKV) {
    int l = j / 49152, r = j % 49152; int n = r >> 7, k = r & 127;
    v = qkv[((size_t)l * 128 + k) * 384 + n];
  } else {
    j -= SZ_QKV;
    if (j < SZ_WO) {
      int l = j >> 14, r = j & 16383; int n = r >> 7, k = r & 127;
      v = wo[((size_t)l * 128 + k) * 128 + n];
    } else {
      j -= SZ_WO;
      if (j < SZ_W1) {
        int l = j >> 16, r = j & 65535; int n = r >> 7, k = r & 127;
        v = w1[((size_t)l * 128 + k) * 512 + n];
      } else {
        j -= SZ_W1;
        if (j < SZ_W2) {
          int l = j >> 16, r = j & 65535; int n = r >> 9, k = r & 511;
          v = w2[((size_t)l * 512 + k) * 128 + n];
        } else {
          j -= SZ_W2;
          int n = j >> 7, k = j & 127;
          v = proj[(size_t)k * 384 + n];
        }
      }
    }
  }
  out[i] = (bf16)v;
}

// ---------------- init embeddings (bf16) ----------------
__global__ __launch_bounds__(256) void init_kernel(
    const float* __restrict__ depot, const float* __restrict__ loc, const float* __restrict__ demand,
    const float* __restrict__ Wn, const float* __restrict__ bn_, const float* __restrict__ Wd,
    const float* __restrict__ bd, bf16* __restrict__ hb) {
  int idx = blockIdx.x * 256 + threadIdx.x;
  if (idx >= ROWS * D_) return;
  int c = idx & 127;
  int row = idx >> 7;
  int b = row / NT_;
  int n = row - b * NT_;
  float v;
  if (n < 2) {
    const float* dp = depot + (b * 2 + n) * 2;
    v = dp[0] * Wd[c] + dp[1] * Wd[D_ + c] + bd[c];
  } else {
    int i = n - 2;
    const float* lp = loc + ((size_t)b * 1000 + i) * 2;
    v = lp[0] * Wn[c] + lp[1] * Wn[D_ + c] + demand[b * 1000 + i] * Wn[2 * D_ + c] + bn_[c];
  }
  hb[idx] = (bf16)v;
}

// ---------------- staging helper: 64x128 A tile -> swizzled LDS, optional BN ----------------
template<bool BNA>
__device__ __forceinline__ void stageA(
    bf16* __restrict__ A1, const bf16* __restrict__ A, int bm, int tid,
    const float* __restrict__ miA) {
#pragma unroll
  for (int it = 0; it < 4; ++it) {
    int idx = it * 256 + tid;
    int row = idx >> 4, seg = idx & 15;
    bf16x8 x = *(const bf16x8*)&A[(size_t)(bm + row) * 128 + seg * 8];
    if (BNA) {
      int kc = seg * 8;
      f32x4 s0 = *(const f32x4*)&miA[kc],       s1 = *(const f32x4*)&miA[kc + 4];
      f32x4 c0 = *(const f32x4*)&miA[128 + kc], c1 = *(const f32x4*)&miA[128 + kc + 4];
      bf16x8 y;
#pragma unroll
      for (int i = 0; i < 4; ++i) y[i] = (bf16)__builtin_fmaf((float)x[i], s0[i], c0[i]);
#pragma unroll
      for (int i = 0; i < 4; ++i) y[4 + i] = (bf16)__builtin_fmaf((float)x[4 + i], s1[i], c1[i]);
      *(bf16x8*)&A1[UNITX(row, seg) * 8] = y;
    } else {
      *(bf16x8*)&A1[UNITX(row, seg) * 8] = x;
    }
  }
}

// ---------------- MFMA GEMM v3: A staged once, B direct from global (L2) ----------------
// tile 64(M) x 128(N), K=128. STATS partials column-major ps[(bn+c)*512 + by]
template<int N_, bool BIAS, bool RELU, bool RES, bool STATS, bool BNA, bool BNR>
__global__ __launch_bounds__(256) void mgemm(
    const bf16* __restrict__ A, const bf16* __restrict__ Wt,
    const float* __restrict__ bias, const bf16* __restrict__ R, bf16* __restrict__ Cout,
    float* __restrict__ ps, float* __restrict__ pq,
    const float* __restrict__ miA, const float* __restrict__ miR) {
  __shared__ bf16 A1[8192];
  __shared__ float sredS[4][64];
  __shared__ float sredQ[4][64];
  int tid = threadIdx.x;
  int w = tid >> 6, l = tid & 63;
  int bm = blockIdx.y * 64, bn = blockIdx.x * 128;
  int wr = (w >> 1) * 32, wc = (w & 1) * 64;
  stageA<BNA>(A1, A, bm, tid, miA);
  __syncthreads();
  f32x4 acc[2][4] = {};
#pragma unroll
  for (int k0 = 0; k0 < 4; ++k0) {
    int seg = k0 * 4 + (l >> 4);
    bf16x8 af[2], bfr[4];
#pragma unroll
    for (int mi = 0; mi < 2; ++mi)
      af[mi] = *(const bf16x8*)&A1[((((wr >> 4) + mi) * 16 + seg) * 16 + ((l & 15) ^ seg)) * 8];
#pragma unroll
    for (int ni = 0; ni < 4; ++ni)
      bfr[ni] = *(const bf16x8*)&Wt[(size_t)(bn + wc + ni * 16 + (l & 15)) * 128 + k0 * 32 + (l >> 4) * 8];
#pragma unroll
    for (int mi = 0; mi < 2; ++mi)
#pragma unroll
      for (int ni = 0; ni < 4; ++ni)
        acc[mi][ni] = MFMA16(af[mi], bfr[ni], acc[mi][ni]);
  }
  float scol[4] = {}, qcol[4] = {};
#pragma unroll
  for (int mi = 0; mi < 2; ++mi)
#pragma unroll
    for (int ni = 0; ni < 4; ++ni) {
      int col = bn + wc + ni * 16 + (l & 15);
      float rs = 1.f, rb = 0.f;
      if (RES && BNR) { rs = miR[col]; rb = miR[128 + col]; }
#pragma unroll
      for (int r = 0; r < 4; ++r) {
        int row = bm + wr + mi * 16 + (l >> 4) * 4 + r;
        float v = acc[mi][ni][r];
        if (BIAS) v += bias[col];
        if (RELU) v = fmaxf(v, 0.f);
        if (RES) {
          float x = (float)R[(size_t)row * N_ + col];
          v += BNR ? __builtin_fmaf(x, rs, rb) : x;
        }
        if (STATS) { scol[ni] += v; qcol[ni] += v * v; }
        Cout[(size_t)row * N_ + col] = (bf16)v;
      }
    }
  if (STATS) {
#pragma unroll
    for (int ni = 0; ni < 4; ++ni) {
      scol[ni] += __shfl_xor(scol[ni], 16); scol[ni] += __shfl_xor(scol[ni], 32);
      qcol[ni] += __shfl_xor(qcol[ni], 16); qcol[ni] += __shfl_xor(qcol[ni], 32);
    }
    __syncthreads();
    if (l < 16) {
#pragma unroll
      for (int ni = 0; ni < 4; ++ni) {
        sredS[w][ni * 16 + l] = scol[ni];
        sredQ[w][ni * 16 + l] = qcol[ni];
      }
    }
    __syncthreads();
    if (tid < 128) {
      int c = tid, cw = c >> 6, cc = c & 63;
      ps[(size_t)(bn + c) * 512 + blockIdx.y] = sredS[cw][cc] + sredS[cw + 2][cc];
      pq[(size_t)(bn + c) * 512 + blockIdx.y] = sredQ[cw][cc] + sredQ[cw + 2][cc];
    }
  }
}

// ---------------- QKV GEMM v3: x=0 -> Q, x=1 -> K, x=2 -> V(transposed) ----------------
template<bool BNA>
__global__ __launch_bounds__(256) void mgemm_qkv(
    const bf16* __restrict__ A, const bf16* __restrict__ Wt, const float* __restrict__ miA,
    bf16* __restrict__ Qh, bf16* __restrict__ Kh, bf16* __restrict__ Vh) {
  __shared__ bf16 smem[8704];          // A1 (8192) | Vt2 (128x68) alias
  bf16* A1 = smem;
  bf16* Vt2 = smem;
  int tid = threadIdx.x;
  int w = tid >> 6, l = tid & 63;
  int bm = blockIdx.y * 64, bn = blockIdx.x * 128;
  int wr = (w >> 1) * 32, wc = (w & 1) * 64;
  stageA<BNA>(A1, A, bm, tid, miA);
  __syncthreads();
  f32x4 acc[2][4] = {};
#pragma unroll
  for (int k0 = 0; k0 < 4; ++k0) {
    int seg = k0 * 4 + (l >> 4);
    bf16x8 af[2], bfr[4];
#pragma unroll
    for (int mi = 0; mi < 2; ++mi)
      af[mi] = *(const bf16x8*)&A1[((((wr >> 4) + mi) * 16 + seg) * 16 + ((l & 15) ^ seg)) * 8];
#pragma unroll
    for (int ni = 0; ni < 4; ++ni)
      bfr[ni] = *(const bf16x8*)&Wt[(size_t)(bn + wc + ni * 16 + (l & 15)) * 128 + k0 * 32 + (l >> 4) * 8];
#pragma unroll
    for (int mi = 0; mi < 2; ++mi)
#pragma unroll
      for (int ni = 0; ni < 4; ++ni)
        acc[mi][ni] = MFMA16(af[mi], bfr[ni], acc[mi][ni]);
  }
  if (blockIdx.x < 2) {
    bf16* dst = (blockIdx.x == 0) ? Qh : Kh;
#pragma unroll
    for (int ni = 0; ni < 4; ++ni) {
      int cl = wc + ni * 16 + (l & 15);
      int hd = cl >> 4, c16 = cl & 15;
#pragma unroll
      for (int mi = 0; mi < 2; ++mi)
#pragma unroll
        for (int r = 0; r < 4; ++r) {
          int row = bm + wr + mi * 16 + (l >> 4) * 4 + r;
          int b = row / NT_;
          int n = row - b * NT_;
          dst[(((size_t)b * 8 + hd) * NTP + n) * 16 + c16] = (bf16)acc[mi][ni][r];
        }
    }
  } else {
    __syncthreads();
#pragma unroll
    for (int mi = 0; mi < 2; ++mi)
#pragma unroll
      for (int ni = 0; ni < 4; ++ni) {
        int cl = wc + ni * 16 + (l & 15);
        int r0 = wr + mi * 16 + (l >> 4) * 4;
        bf16x4 pk;
#pragma unroll
        for (int r = 0; r < 4; ++r) pk[r] = (bf16)acc[mi][ni][r];
        *(bf16x4*)&Vt2[cl * 68 + r0] = pk;
      }
    __syncthreads();
    int colg = tid >> 4, nl = tid & 15;
#pragma unroll
    for (int ci = 0; ci < 8; ++ci) {
      int lc = colg + ci * 16;
      int hd = lc >> 4, c16 = lc & 15;
#pragma unroll
      for (int ri = 0; ri < 4; ++ri) {
        int lrow = nl + ri * 16;
        int row = bm + lrow;
        int b = row / NT_;
        int n = row - b * NT_;
        Vh[(((size_t)b * 8 + hd) * 16 + c16) * NTP + n] = Vt2[lc * 68 + lrow];
      }
    }
  }
}

// ---------------- fused FF v2: weights direct from global, A1 staged once ----------------
// y = relu(bn1(x)@W1+b1)@W2 + b2 + bn1(x), + stats.  one block = 64 rows.
__global__ __launch_bounds__(256) void fffused(
    const bf16* __restrict__ X, const float* __restrict__ mi,
    const bf16* __restrict__ W1t, const float* __restrict__ bias1,
    const bf16* __restrict__ W2t, const float* __restrict__ bias2,
    bf16* __restrict__ Y, float* __restrict__ ps, float* __restrict__ pq) {
  __shared__ bf16 A1[8192];   // 64 x 128, UNITX swizzled
  __shared__ bf16 A2[8192];   // 64 x 128 (ff chunk), plain unit-linear
  __shared__ float sredS[4][64];
  __shared__ float sredQ[4][64];
  int tid = threadIdx.x;
  int w = tid >> 6, l = tid & 63;
  int bm = blockIdx.x * 64;
  stageA<true>(A1, X, bm, tid, mi);
  __syncthreads();
  int wr = (w >> 1) * 32, wc = (w & 1) * 64;
  f32x4 acc2[2][4] = {};

  for (int nc = 0; nc < 4; ++nc) {
    // stage 1: ff1^T chunk; A-operand = W1 rows (direct global), B-operand = h rows (A1)
    f32x4 acc1[2][4] = {};
#pragma unroll
    for (int k0 = 0; k0 < 4; ++k0) {
      int seg = k0 * 4 + (l >> 4);
      bf16x8 af[2], hf[4];
#pragma unroll
      for (int m2 = 0; m2 < 2; ++m2)
        af[m2] = *(const bf16x8*)&W1t[(size_t)(nc * 128 + w * 32 + m2 * 16 + (l & 15)) * 128 + k0 * 32 + (l >> 4) * 8];
#pragma unroll
      for (int ni = 0; ni < 4; ++ni)
        hf[ni] = *(const bf16x8*)&A1[((ni * 16 + seg) * 16 + ((l & 15) ^ seg)) * 8];
#pragma unroll
      for (int m2 = 0; m2 < 2; ++m2)
#pragma unroll
        for (int ni = 0; ni < 4; ++ni)
          acc1[m2][ni] = MFMA16(af[m2], hf[ni], acc1[m2][ni]);
    }
    __syncthreads();   // prev chunk's stage-2 A2 reads complete
    // pack ff1 chunk to A2: lane holds 4 consecutive ffk for one hrow
#pragma unroll
    for (int m2 = 0; m2 < 2; ++m2) {
      int ffk0 = w * 32 + m2 * 16 + (l >> 4) * 4;   // 0..127, multiple of 4
      int seg = ffk0 >> 3, half = ffk0 & 7;
#pragma unroll
      for (int ni = 0; ni < 4; ++ni) {
        bf16x4 pk;
#pragma unroll
        for (int r = 0; r < 4; ++r) {
          float v = acc1[m2][ni][r] + bias1[nc * 128 + ffk0 + r];
          pk[r] = (bf16)fmaxf(v, 0.f);
        }
        *(bf16x4*)&A2[(ni * 256 + seg * 16 + (l & 15)) * 8 + half] = pk;
      }
    }
    __syncthreads();   // A2 ready
    // stage 2: acc2 += A2 x W2 (direct global)
#pragma unroll
    for (int k0 = 0; k0 < 4; ++k0) {
      bf16x8 a2f[2], b2f[4];
#pragma unroll
      for (int m2 = 0; m2 < 2; ++m2)
        a2f[m2] = *(const bf16x8*)&A2[(((wr >> 4) + m2) * 256 + (k0 * 4 + (l >> 4)) * 16 + (l & 15)) * 8];
#pragma unroll
      for (int ni = 0; ni < 4; ++ni)
        b2f[ni] = *(const bf16x8*)&W2t[(size_t)(wc + ni * 16 + (l & 15)) * 512 + nc * 128 + k0 * 32 + (l >> 4) * 8];
#pragma unroll
      for (int m2 = 0; m2 < 2; ++m2)
#pragma unroll
        for (int ni = 0; ni < 4; ++ni)
          acc2[m2][ni] = MFMA16(a2f[m2], b2f[ni], acc2[m2][ni]);
    }
  }
  // epilogue: + b2 + residual(A1) + stats + store
  float scol[4] = {}, qcol[4] = {};
#pragma unroll
  for (int m2 = 0; m2 < 2; ++m2)
#pragma unroll
    for (int ni = 0; ni < 4; ++ni) {
      int col = wc + ni * 16 + (l & 15);
      float bb = bias2[col];
#pragma unroll
      for (int r = 0; r < 4; ++r) {
        int row = wr + m2 * 16 + (l >> 4) * 4 + r;
        float res = (float)A1[UNITX(row, col >> 3) * 8 + (col & 7)];
        float v = acc2[m2][ni][r] + bb + res;
        scol[ni] += v; qcol[ni] += v * v;
        Y[(size_t)(bm + row) * 128 + col] = (bf16)v;
      }
    }
#pragma unroll
  for (int ni = 0; ni < 4; ++ni) {
    scol[ni] += __shfl_xor(scol[ni], 16); scol[ni] += __shfl_xor(scol[ni], 32);
    qcol[ni] += __shfl_xor(qcol[ni], 16); qcol[ni] += __shfl_xor(qcol[ni], 32);
  }
  __syncthreads();
  if (l < 16) {
#pragma unroll
    for (int ni = 0; ni < 4; ++ni) {
      sredS[w][ni * 16 + l] = scol[ni];
      sredQ[w][ni * 16 + l] = qcol[ni];
    }
  }
  __syncthreads();
  if (tid < 128) {
    int c = tid, cw = c >> 6, cc = c & 63;
    ps[(size_t)c * 512 + blockIdx.x] = sredS[cw][cc] + sredS[cw + 2][cc];
    pq[(size_t)c * 512 + blockIdx.x] = sredQ[cw][cc] + sredQ[cw + 2][cc];
  }
}

// ---------------- MFMA flash attention (unchanged: 58 us) ----------------
__global__ __launch_bounds__(256) void mattn(
    const bf16* __restrict__ Qh, const bf16* __restrict__ Kh,
    const bf16* __restrict__ Vh, bf16* __restrict__ ab) {
  __shared__ bf16 KsF[1024];
  __shared__ bf16 VtF[1024];
  __shared__ bf16 PsF[4][2048];
  int tid = threadIdx.x;
  int w = tid >> 6, l = tid & 63;
  int bh = blockIdx.x;
  int b = bh >> 3, hd = bh & 7;
  const bf16* Qp = Qh + (size_t)bh * NTP * 16;
  const bf16* Kp = Kh + (size_t)bh * NTP * 16;
  const bf16* Vp = Vh + (size_t)bh * 16 * NTP;
  int qbase = blockIdx.y * 128 + w * 32;
  int qrow = qbase + (l & 31); if (qrow >= NT_) qrow = NT_ - 1;
  bf16x8 qf = *(const bf16x8*)&Qp[qrow * 16 + (l >> 5) * 8];

  const float SC = 0.25f * 1.44269504088896f;
  const float MC = 8.0f * SC;
  f32x4 oacc[2] = {};
  f32x4 lacc[2] = {};
  bf16x8 ones;
#pragma unroll
  for (int i = 0; i < 8; ++i) ones[i] = (bf16)1.0f;
  const f32x16 zz = {0,0,0,0,0,0,0,0,0,0,0,0,0,0,0,0};

  for (int t = 0; t < 16; ++t) {
    int kb = t * 64;
    __syncthreads();
    if (tid < 128) {
      int key = (tid >> 6) * 32 + (tid & 31);
      int h2 = (tid >> 5) & 1;
      int krow = kb + key; if (krow >= NT_) krow = NT_ - 1;
      *(bf16x8*)&KsF[tid * 8] = *(const bf16x8*)&Kp[krow * 16 + h2 * 8];
    } else {
      int u = tid - 128;
      int seg = u >> 4, dim = u & 15;
      *(bf16x8*)&VtF[u * 8] = *(const bf16x8*)&Vp[dim * NTP + kb + seg * 8];
    }
    __syncthreads();

    f32x16 sv[2];
#pragma unroll
    for (int c = 0; c < 2; ++c) {
      bf16x8 kf = *(const bf16x8*)&KsF[(c * 64 + l) * 8];
      sv[c] = __builtin_amdgcn_mfma_f32_32x32x16_bf16(kf, qf, zz, 0, 0, 0);
    }
    if (kb + 64 > NT_) {
#pragma unroll
      for (int c = 0; c < 2; ++c)
#pragma unroll
        for (int r = 0; r < 16; ++r) {
          int key = kb + c * 32 + (r & 3) + 8 * (r >> 2) + 4 * (l >> 5);
          if (key >= NT_) sv[c][r] = -1e30f;
        }
    }
#pragma unroll
    for (int c = 0; c < 2; ++c)
#pragma unroll
      for (int r = 0; r < 16; ++r)
        sv[c][r] = EXP2(__builtin_fmaf(sv[c][r], SC, -MC));
    {
      int q = l & 31;
      int qh4 = q >> 4, ql = q & 15, half = (l >> 5) * 4;
#pragma unroll
      for (int c = 0; c < 2; ++c)
#pragma unroll
        for (int g2 = 0; g2 < 4; ++g2) {
          bf16x4 pk;
#pragma unroll
          for (int i = 0; i < 4; ++i) pk[i] = (bf16)sv[c][g2 * 4 + i];
          int unit = (c * 2 + qh4) * 64 + g2 * 16 + ql;
          *(bf16x4*)&PsF[w][unit * 8 + half] = pk;
        }
    }
#pragma unroll
    for (int kh = 0; kh < 2; ++kh) {
      bf16x8 vf = *(const bf16x8*)&VtF[(kh * 64 + l) * 8];
#pragma unroll
      for (int g = 0; g < 2; ++g) {
        bf16x8 pf = *(const bf16x8*)&PsF[w][((kh * 2 + g) * 64 + l) * 8];
        oacc[g] = MFMA16(pf, vf, oacc[g]);
        lacc[g] = MFMA16(pf, ones, lacc[g]);
      }
    }
  }
#pragma unroll
  for (int g = 0; g < 2; ++g)
#pragma unroll
    for (int r = 0; r < 4; ++r) {
      int qq = qbase + g * 16 + (l >> 4) * 4 + r;
      if (qq < NT_)
        ab[((size_t)b * NT_ + qq) * 128 + hd * 16 + (l & 15)] = (bf16)(oacc[g][r] / lacc[g][r]);
    }
}

// ---------------- BN finalize (parallel, column-major partials) ----------------
__global__ __launch_bounds__(512) void stats_final(
    const float* __restrict__ ps, const float* __restrict__ pq,
    const float* __restrict__ sc, const float* __restrict__ bi, float* __restrict__ mi) {
  int tid = threadIdx.x;
  int c = tid >> 2, q4 = tid & 3;
  float s = 0.f, q = 0.f;
  for (int p = q4; p < 501; p += 4) { s += ps[c * 512 + p]; q += pq[c * 512 + p]; }
  s += __shfl_xor(s, 1); s += __shfl_xor(s, 2);
  q += __shfl_xor(q, 1); q += __shfl_xor(q, 2);
  if (q4 == 0) {
    float mean = s * (1.f / (float)ROWS);
    float var = q * (1.f / (float)ROWS) - mean * mean;
    float s2 = sc[c] * rsqrtf(var + 1e-5f);
    mi[c] = s2;
    mi[128 + c] = bi[c] - mean * s2;
  }
}

// ---------------- decoder ----------------
__global__ void ge_partial(const bf16* __restrict__ X, const float* __restrict__ mi,
                           float* __restrict__ part) {
  int b = blockIdx.x, ch = blockIdx.y, d = threadIdx.x;
  int n0 = ch * 126, n1 = n0 + 126; if (n1 > NT_) n1 = NT_;
  float sS = mi[d], sB = mi[128 + d];
  float s = 0.f;
  for (int n = n0; n < n1; ++n)
    s += __builtin_fmaf((float)X[((size_t)b * NT_ + n) * D_ + d], sS, sB);
  part[(b * 8 + ch) * D_ + d] = s;
}

__global__ void query_kernel(const float* __restrict__ part, const bf16* __restrict__ X,
                             const float* __restrict__ mi,
                             const float* __restrict__ Wf, const float* __restrict__ Ws,
                             float* __restrict__ qry) {
  __shared__ float sge[128], sh0[128];
  int b = blockIdx.x, d = threadIdx.x;
  float s = 0.f;
#pragma unroll
  for (int ch = 0; ch < 8; ++ch) s += part[(b * 8 + ch) * D_ + d];
  sge[d] = s * (1.f / (float)NT_);
  sh0[d] = __builtin_fmaf((float)X[(size_t)b * NT_ * D_ + d], mi[d], mi[128 + d]);
  __syncthreads();
  float q = 0.f;
  for (int k = 0; k < 128; ++k) q += sge[k] * Wf[k * D_ + d] + sh0[k] * Ws[k * D_ + d];
  qry[b * D_ + d] = q;
}

__global__ __launch_bounds__(256) void glimpse_kernel(
    const bf16* __restrict__ proj, const float* __restrict__ qry,
    const int* __restrict__ mask, float* __restrict__ glimpse) {
  int bid = blockIdx.x; int b = bid >> 3, hd = bid & 7;
  int tid = threadIdx.x;
  __shared__ float sq[16];
  __shared__ float sex[NT_];
  __shared__ float rmax[4];
  __shared__ float wacc[4][17];
  if (tid < 16) sq[tid] = qry[b * 128 + hd * 16 + tid];
  __syncthreads();
  const bf16* P = proj + (size_t)b * NT_ * 384;
  const int* Mk = mask + b * NT_;
  float lmax = -1e30f;
#pragma unroll
  for (int it = 0; it < 4; ++it) {
    int n = tid + it * 256;
    if (n < NT_) {
      float c = NEGV;
      if (!Mk[n]) {
        const bf16* kp = &P[(size_t)n * 384 + hd * 16];
        bf16x8 k0 = *(const bf16x8*)kp, k1 = *(const bf16x8*)(kp + 8);
        float d = 0.f;
#pragma unroll
        for (int i = 0; i < 8; ++i) d += sq[i] * (float)k0[i] + sq[8 + i] * (float)k1[i];
        c = d * 0.25f;
      }
      sex[n] = c;
      lmax = fmaxf(lmax, c);
    }
  }
#pragma unroll
  for (int o = 32; o > 0; o >>= 1) lmax = fmaxf(lmax, __shfl_xor(lmax, o));
  if ((tid & 63) == 0) rmax[tid >> 6] = lmax;
  __syncthreads();
  float mx = fmaxf(fmaxf(rmax[0], rmax[1]), fmaxf(rmax[2], rmax[3]));
  float acc[16];
#pragma unroll
  for (int i = 0; i < 16; ++i) acc[i] = 0.f;
  float lsum = 0.f;
#pragma unroll
  for (int it = 0; it < 4; ++it) {
    int n = tid + it * 256;
    if (n < NT_) {
      float e = __expf(sex[n] - mx);
      lsum += e;
      const bf16* vp = &P[(size_t)n * 384 + 128 + hd * 16];
      bf16x8 v0 = *(const bf16x8*)vp, v1 = *(const bf16x8*)(vp + 8);
#pragma unroll
      for (int i = 0; i < 8; ++i) { acc[i] += e * (float)v0[i]; acc[8 + i] += e * (float)v1[i]; }
    }
  }
#pragma unroll
  for (int o = 32; o > 0; o >>= 1) {
    lsum += __shfl_xor(lsum, o);
#pragma unroll
    for (int i = 0; i < 16; ++i) acc[i] += __shfl_xor(acc[i], o);
  }
  if ((tid & 63) == 0) {
    wacc[tid >> 6][16] = lsum;
#pragma unroll
    for (int i = 0; i < 16; ++i) wacc[tid >> 6][i] = acc[i];
  }
  __syncthreads();
  if (tid < 16) {
    float a = wacc[0][tid] + wacc[1][tid] + wacc[2][tid] + wacc[3][tid];
    float L = wacc[0][16] + wacc[1][16] + wacc[2][16] + wacc[3][16];
    glimpse[b * 128 + hd * 16 + tid] = a / L;
  }
}

__global__ void g2_kernel(const float* __restrict__ glimpse, const float* __restrict__ Wout,
                          float* __restrict__ g2) {
  __shared__ float sg[128];
  int b = blockIdx.x, d = threadIdx.x;
  sg[d] = glimpse[b * 128 + d];
  __syncthreads();
  float s = 0.f;
  for (int k = 0; k < 128; ++k) s += sg[k] * Wout[k * 128 + d];
  g2[b * 128 + d] = s;
}

__global__ __launch_bounds__(256) void logits_kernel(
    const bf16* __restrict__ proj, const float* __restrict__ g2,
    const int* __restrict__ mask, float* __restrict__ logits) {
  int b = blockIdx.y;
  int n = blockIdx.x * 256 + threadIdx.x;
  __shared__ float sg[128];
  if (threadIdx.x < 128) sg[threadIdx.x] = g2[b * 128 + threadIdx.x];
  __syncthreads();
  if (n >= NT_) return;
  const bf16* kp = &proj[((size_t)b * NT_ + n) * 384 + 256];
  float d = 0.f;
#pragma unroll
  for (int j = 0; j < 16; ++j) {
    bf16x8 v = *(const bf16x8*)&kp[j * 8];
#pragma unroll
    for (int i = 0; i < 8; ++i) d += sg[j * 8 + i] * (float)v[i];
  }
  d = 10.f * tanhf(d * 0.088388347648318447f);
  logits[b * NT_ + n] = mask[b * NT_ + n] ? NEGV : d;
}

__global__ __launch_bounds__(256) void lsm_kernel(const float* __restrict__ logits, float* __restrict__ out) {
  int b = blockIdx.x, tid = threadIdx.x;
  __shared__ float red[256];
  float mx = -1e30f;
  for (int n = tid; n < NT_; n += 256) mx = fmaxf(mx, logits[b * NT_ + n]);
  red[tid] = mx; __syncthreads();
  for (int s = 128; s > 0; s >>= 1) { if (tid < s) red[tid] = fmaxf(red[tid], red[tid + s]); __syncthreads(); }
  mx = red[0]; __syncthreads();
  float sm = 0.f;
  for (int n = tid; n < NT_; n += 256) sm += __expf(logits[b * NT_ + n] - mx);
  red[tid] = sm; __syncthreads();
  for (int s = 128; s > 0; s >>= 1) { if (tid < s) red[tid] += red[tid + s]; __syncthreads(); }
  float lse = mx + logf(red[0]);
  for (int n = tid; n < NT_; n += 256) out[(size_t)b * NT_ + n] = logits[b * NT_ + n] - lse;
}

// ---------------- launcher ----------------
extern "C" void kernel_launch(void* const* d_in, const int* in_sizes, int n_in,
                              void* d_out, int out_size, void* d_ws, size_t ws_size,
                              hipStream_t stream) {
  const float* depot        = (const float*)d_in[0];
  const float* loc          = (const float*)d_in[1];
  const float* demand       = (const float*)d_in[2];
  const int*   mask         = (const int*)d_in[3];
  const float* W_init_node  = (const float*)d_in[4];
  const float* b_init_node  = (const float*)d_in[5];
  const float* W_init_depot = (const float*)d_in[6];
  const float* b_init_depot = (const float*)d_in[7];
  const float* enc_Wqkv     = (const float*)d_in[8];
  const float* enc_Wo       = (const float*)d_in[9];
  const float* enc_W1       = (const float*)d_in[10];
  const float* enc_b1       = (const float*)d_in[11];
  const float* enc_W2       = (const float*)d_in[12];
  const float* enc_b2       = (const float*)d_in[13];
  const float* bn1_s        = (const float*)d_in[14];
  const float* bn1_b        = (const float*)d_in[15];
  const float* bn2_s        = (const float*)d_in[16];
  const float* bn2_b        = (const float*)d_in[17];
  const float* W_proj       = (const float*)d_in[18];
  const float* W_fixed      = (const float*)d_in[19];
  const float* W_step       = (const float*)d_in[20];
  const float* W_out        = (const float*)d_in[21];
  float* out = (float*)d_out;

  char* base = (char*)d_ws;
  bf16*  hb0   = (bf16*)(base);                        // 8,208,384
  bf16*  ab    = (bf16*)(base + 8208384);              // 8,208,384
  bf16*  Qh    = (bf16*)(base + 16416768);             // 8,388,608 [bh][NTP][16]
  bf16*  Kh    = (bf16*)(base + 24805376);             // 8,388,608
  bf16*  Vh    = (bf16*)(base + 33193984);             // 8,388,608 [bh*16+c16][NTP]
  bf16*  xb1   = Qh;                                   // alias (post-mattn lifetime)
  bf16*  xb2   = (bf16*)(base + 41582592);             // 8,208,384
  bf16*  projb = (bf16*)(base + 49790976);             // 24,625,152
  bf16*  wb    = (bf16*)(base + 74416128);             // 884,736
  float* ps    = (float*)(base + 75300864);            // 262,144 [128 col][512]
  float* pq    = (float*)(base + 75563008);            // 262,144
  float* mi1   = (float*)(base + 75825152);            // 1,024
  float* mi2   = (float*)(base + 75826176);            // 1,024
  float* qry   = (float*)(base + 75827200);            // 16,384
  float* glim  = (float*)(base + 75843584);            // 16,384
  float* g2    = (float*)(base + 75859968);            // 16,384
  float* gep   = ps;                                   // decoder reuse
  float* logit = pq;                                   // decoder reuse

  bf16* wt_qkv  = wb;
  bf16* wt_wo   = wb + SZ_QKV;
  bf16* wt_w1   = wb + SZ_QKV + SZ_WO;
  bf16* wt_w2   = wb + SZ_QKV + SZ_WO + SZ_W1;
  bf16* wt_proj = wb + SZ_QKV + SZ_WO + SZ_W1 + SZ_W2;

  prep_w<<<1728, 256, 0, stream>>>(enc_Wqkv, enc_Wo, enc_W1, enc_W2, W_proj, wb);
  init_kernel<<<(ROWS * D_ + 255) / 256, 256, 0, stream>>>(
      depot, loc, demand, W_init_node, b_init_node, W_init_depot, b_init_depot, hb0);

  for (int l = 0; l < 2; ++l) {
    const bf16* hin = (l == 0) ? hb0 : xb2;
    if (l == 0)
      mgemm_qkv<false><<<dim3(3, 501), 256, 0, stream>>>(hin, wt_qkv, nullptr, Qh, Kh, Vh);
    else
      mgemm_qkv<true><<<dim3(3, 501), 256, 0, stream>>>(hin, wt_qkv + (size_t)384 * 128, mi2, Qh, Kh, Vh);
    mattn<<<dim3(256, 8), 256, 0, stream>>>(Qh, Kh, Vh, ab);
    if (l == 0)
      mgemm<128, false, false, true, true, false, false><<<dim3(1, 501), 256, 0, stream>>>(
          ab, wt_wo, nullptr, hin, xb1, ps, pq, nullptr, nullptr);
    else
      mgemm<128, false, false, true, true, false, true><<<dim3(1, 501), 256, 0, stream>>>(
          ab, wt_wo + (size_t)128 * 128, nullptr, hin, xb1, ps, pq, nullptr, mi2);
    stats_final<<<1, 512, 0, stream>>>(ps, pq, bn1_s + l * D_, bn1_b + l * D_, mi1);
    fffused<<<501, 256, 0, stream>>>(
        xb1, mi1, wt_w1 + (size_t)l * 512 * 128, enc_b1 + (size_t)l * FF_,
        wt_w2 + (size_t)l * 128 * 512, enc_b2 + (size_t)l * D_, xb2, ps, pq);
    stats_final<<<1, 512, 0, stream>>>(ps, pq, bn2_s + l * D_, bn2_b + l * D_, mi2);
  }

  // decoder
  mgemm<384, false, false, false, false, true, false><<<dim3(3, 501), 256, 0, stream>>>(
      xb2, wt_proj, nullptr, nullptr, projb, nullptr, nullptr, mi2, nullptr);
  ge_partial<<<dim3(32, 8), 128, 0, stream>>>(xb2, mi2, gep);
  query_kernel<<<32, 128, 0, stream>>>(gep, xb2, mi2, W_fixed, W_step, qry);
  glimpse_kernel<<<256, 256, 0, stream>>>(projb, qry, mask, glim);
  g2_kernel<<<32, 128, 0, stream>>>(glim, W_out, g2);
  logits_kernel<<<dim3(4, 32), 256, 0, stream>>>(projb, g2, mask, logit);
  lsm_kernel<<<32, 256, 0, stream>>>(logit, out);
}

// Round 10
// 387.710 us; speedup vs baseline: 1.0339x; 1.0339x over previous
//
#include <hip/hip_runtime.h>

#define B_   32
#define NT_  1002
#define D_   128
#define H_   8
#define FF_  512
#define ROWS (B_ * NT_)          // 32064 = 501*64
#define NEGV (-1e9f)
#define NTP  1024                // padded rows per (b,head)

typedef __bf16 bf16;
typedef __bf16 bf16x8 __attribute__((ext_vector_type(8)));
typedef __bf16 bf16x4 __attribute__((ext_vector_type(4)));
typedef float  f32x4  __attribute__((ext_vector_type(4)));
typedef float  f32x16 __attribute__((ext_vector_type(16)));

#if __has_builtin(__builtin_amdgcn_exp2f)
#define EXP2(x) __builtin_amdgcn_exp2f(x)
#else
#define EXP2(x) exp2f(x)
#endif

#define MFMA16(a, b, c) __builtin_amdgcn_mfma_f32_16x16x32_bf16(a, b, c, 0, 0, 0)
#define MFMA32(a, b, c) __builtin_amdgcn_mfma_f32_32x32x16_bf16(a, b, c, 0, 0, 0)

__device__ __forceinline__ unsigned pkbf(float lo, float hi) {
  unsigned r;
  asm("v_cvt_pk_bf16_f32 %0, %1, %2" : "=v"(r) : "v"(lo), "v"(hi));
  return r;
}

// unit-linear LDS tile addressing: 16B unit for (row, 8-elem k-seg), 32-k tiles
__device__ __forceinline__ int UNIT(int row, int seg) {
  return (row >> 4) * 64 + seg * 16 + (row & 15);
}
// 128-k tiles (16 segs)
__device__ __forceinline__ int UNIT128(int row, int seg) {
  return (row >> 4) * 256 + seg * 16 + (row & 15);
}

// ---------------- weight prep: transpose + convert to bf16 [n][k] ----------------
#define SZ_QKV (2*384*128)
#define SZ_WO  (2*128*128)
#define SZ_W1  (2*512*128)
#define SZ_W2  (2*128*512)
#define SZ_PROJ (384*128)

__global__ __launch_bounds__(256) void prep_w(
    const float* __restrict__ qkv, const float* __restrict__ wo, const float* __restrict__ w1,
    const float* __restrict__ w2, const float* __restrict__ proj, bf16* __restrict__ out) {
  int i = blockIdx.x * 256 + threadIdx.x;
  int j = i;
  float v;
  if (j < SZ_QKV) {
    int l = j / 49152, r = j % 49152; int n = r >> 7, k = r & 127;
    v = qkv[((size_t)l * 128 + k) * 384 + n];
  } else {
    j -= SZ_QKV;
    if (j < SZ_WO) {
      int l = j >> 14, r = j & 16383; int n = r >> 7, k = r & 127;
      v = wo[((size_t)l * 128 + k) * 128 + n];
    } else {
      j -= SZ_WO;
      if (j < SZ_W1) {
        int l = j >> 16, r = j & 65535; int n = r >> 7, k = r & 127;
        v = w1[((size_t)l * 128 + k) * 512 + n];
      } else {
        j -= SZ_W1;
        if (j < SZ_W2) {
          int l = j >> 16, r = j & 65535; int n = r >> 9, k = r & 511;
          v = w2[((size_t)l * 512 + k) * 128 + n];
        } else {
          j -= SZ_W2;
          int n = j >> 7, k = j & 127;
          v = proj[(size_t)k * 384 + n];
        }
      }
    }
  }
  out[i] = (bf16)v;
}

// ---------------- init embeddings (bf16) ----------------
__global__ __launch_bounds__(256) void init_kernel(
    const float* __restrict__ depot, const float* __restrict__ loc, const float* __restrict__ demand,
    const float* __restrict__ Wn, const float* __restrict__ bn_, const float* __restrict__ Wd,
    const float* __restrict__ bd, bf16* __restrict__ hb) {
  int idx = blockIdx.x * 256 + threadIdx.x;
  if (idx >= ROWS * D_) return;
  int c = idx & 127;
  int row = idx >> 7;
  int b = row / NT_;
  int n = row - b * NT_;
  float v;
  if (n < 2) {
    const float* dp = depot + (b * 2 + n) * 2;
    v = dp[0] * Wd[c] + dp[1] * Wd[D_ + c] + bd[c];
  } else {
    int i = n - 2;
    const float* lp = loc + ((size_t)b * 1000 + i) * 2;
    v = lp[0] * Wn[c] + lp[1] * Wn[D_ + c] + demand[b * 1000 + i] * Wn[2 * D_ + c] + bn_[c];
  }
  hb[idx] = (bf16)v;
}

// ---------------- MFMA GEMM (R8): tile 64(M) x 128(N), LDS-staged A and B ----------------
// A [ROWS][K_] bf16, Wt [N][K] bf16; STATS partials column-major ps[(bn+c)*512 + by]
template<int N_, int K_, bool BIAS, bool RELU, bool RES, bool STATS, bool BNA, bool BNR>
__global__ __launch_bounds__(256) void mgemm(
    const bf16* __restrict__ A, const bf16* __restrict__ Wt,
    const float* __restrict__ bias, const bf16* __restrict__ R, bf16* __restrict__ Cout,
    float* __restrict__ ps, float* __restrict__ pq,
    const float* __restrict__ miA, const float* __restrict__ miR) {
  __shared__ bf16 AsF[2048];
  __shared__ bf16 BsF[4096];
  __shared__ float sredS[4][64];
  __shared__ float sredQ[4][64];
  int tid = threadIdx.x;
  int w = tid >> 6, l = tid & 63;
  int bm = blockIdx.y * 64, bn = blockIdx.x * 128;
  int wr = (w >> 1) * 32, wc = (w & 1) * 64;
  f32x4 acc[2][4] = {};
  int srow = tid >> 2, sseg = tid & 3;
  int uA = UNIT(srow, sseg) * 8;
  int uB0 = UNIT(srow, sseg) * 8, uB1 = UNIT(srow + 64, sseg) * 8;
  for (int k0 = 0; k0 < K_; k0 += 32) {
    __syncthreads();
    {
      bf16x8 x = *(const bf16x8*)&A[(size_t)(bm + srow) * K_ + k0 + sseg * 8];
      if (BNA) {
        int kc = k0 + sseg * 8;
        f32x4 s0 = *(const f32x4*)&miA[kc],       s1 = *(const f32x4*)&miA[kc + 4];
        f32x4 c0 = *(const f32x4*)&miA[128 + kc], c1 = *(const f32x4*)&miA[128 + kc + 4];
        bf16x8 y;
#pragma unroll
        for (int i = 0; i < 4; ++i) y[i] = (bf16)__builtin_fmaf((float)x[i], s0[i], c0[i]);
#pragma unroll
        for (int i = 0; i < 4; ++i) y[4 + i] = (bf16)__builtin_fmaf((float)x[4 + i], s1[i], c1[i]);
        *(bf16x8*)&AsF[uA] = y;
      } else {
        *(bf16x8*)&AsF[uA] = x;
      }
    }
    *(bf16x8*)&BsF[uB0] = *(const bf16x8*)&Wt[(size_t)(bn + srow) * K_ + k0 + sseg * 8];
    *(bf16x8*)&BsF[uB1] = *(const bf16x8*)&Wt[(size_t)(bn + srow + 64) * K_ + k0 + sseg * 8];
    __syncthreads();
    bf16x8 af[2], bfr[4];
#pragma unroll
    for (int mi = 0; mi < 2; ++mi)
      af[mi] = *(const bf16x8*)&AsF[(((wr >> 4) + mi) * 64 + (l >> 4) * 16 + (l & 15)) * 8];
#pragma unroll
    for (int ni = 0; ni < 4; ++ni)
      bfr[ni] = *(const bf16x8*)&BsF[(((wc >> 4) + ni) * 64 + (l >> 4) * 16 + (l & 15)) * 8];
#pragma unroll
    for (int mi = 0; mi < 2; ++mi)
#pragma unroll
      for (int ni = 0; ni < 4; ++ni)
        acc[mi][ni] = MFMA16(af[mi], bfr[ni], acc[mi][ni]);
  }
  float scol[4] = {}, qcol[4] = {};
#pragma unroll
  for (int mi = 0; mi < 2; ++mi)
#pragma unroll
    for (int ni = 0; ni < 4; ++ni) {
      int col = bn + wc + ni * 16 + (l & 15);
      float rs = 1.f, rb = 0.f;
      if (RES && BNR) { rs = miR[col]; rb = miR[128 + col]; }
#pragma unroll
      for (int r = 0; r < 4; ++r) {
        int row = bm + wr + mi * 16 + (l >> 4) * 4 + r;
        float v = acc[mi][ni][r];
        if (BIAS) v += bias[col];
        if (RELU) v = fmaxf(v, 0.f);
        if (RES) {
          float x = (float)R[(size_t)row * N_ + col];
          v += BNR ? __builtin_fmaf(x, rs, rb) : x;
        }
        if (STATS) { scol[ni] += v; qcol[ni] += v * v; }
        Cout[(size_t)row * N_ + col] = (bf16)v;
      }
    }
  if (STATS) {
#pragma unroll
    for (int ni = 0; ni < 4; ++ni) {
      scol[ni] += __shfl_xor(scol[ni], 16); scol[ni] += __shfl_xor(scol[ni], 32);
      qcol[ni] += __shfl_xor(qcol[ni], 16); qcol[ni] += __shfl_xor(qcol[ni], 32);
    }
    __syncthreads();
    if (l < 16) {
#pragma unroll
      for (int ni = 0; ni < 4; ++ni) {
        sredS[w][ni * 16 + l] = scol[ni];
        sredQ[w][ni * 16 + l] = qcol[ni];
      }
    }
    __syncthreads();
    if (tid < 128) {
      int c = tid, cw = c >> 6, cc = c & 63;
      ps[(size_t)(bn + c) * 512 + blockIdx.y] = sredS[cw][cc] + sredS[cw + 2][cc];
      pq[(size_t)(bn + c) * 512 + blockIdx.y] = sredQ[cw][cc] + sredQ[cw + 2][cc];
    }
  }
}

// ---------------- QKV GEMM (R8): x=0 -> Q, x=1 -> K, x=2 -> V(transposed) ----------------
template<bool BNA>
__global__ __launch_bounds__(256) void mgemm_qkv(
    const bf16* __restrict__ A, const bf16* __restrict__ Wt, const float* __restrict__ miA,
    bf16* __restrict__ Qh, bf16* __restrict__ Kh, bf16* __restrict__ Vh) {
  __shared__ bf16 smem[128 * 68];     // As(2048) + Bs(4096) | Vt2(128x68)
  bf16* AsF = smem;
  bf16* BsF = smem + 2048;
  bf16* Vt2 = smem;
  int tid = threadIdx.x;
  int w = tid >> 6, l = tid & 63;
  int bm = blockIdx.y * 64, bn = blockIdx.x * 128;
  int wr = (w >> 1) * 32, wc = (w & 1) * 64;
  f32x4 acc[2][4] = {};
  int srow = tid >> 2, sseg = tid & 3;
  int uA = UNIT(srow, sseg) * 8;
  int uB0 = UNIT(srow, sseg) * 8, uB1 = UNIT(srow + 64, sseg) * 8;
  for (int k0 = 0; k0 < 128; k0 += 32) {
    __syncthreads();
    {
      bf16x8 x = *(const bf16x8*)&A[(size_t)(bm + srow) * 128 + k0 + sseg * 8];
      if (BNA) {
        int kc = k0 + sseg * 8;
        f32x4 s0 = *(const f32x4*)&miA[kc],       s1 = *(const f32x4*)&miA[kc + 4];
        f32x4 c0 = *(const f32x4*)&miA[128 + kc], c1 = *(const f32x4*)&miA[128 + kc + 4];
        bf16x8 y;
#pragma unroll
        for (int i = 0; i < 4; ++i) y[i] = (bf16)__builtin_fmaf((float)x[i], s0[i], c0[i]);
#pragma unroll
        for (int i = 0; i < 4; ++i) y[4 + i] = (bf16)__builtin_fmaf((float)x[4 + i], s1[i], c1[i]);
        *(bf16x8*)&AsF[uA] = y;
      } else {
        *(bf16x8*)&AsF[uA] = x;
      }
    }
    *(bf16x8*)&BsF[uB0] = *(const bf16x8*)&Wt[(size_t)(bn + srow) * 128 + k0 + sseg * 8];
    *(bf16x8*)&BsF[uB1] = *(const bf16x8*)&Wt[(size_t)(bn + srow + 64) * 128 + k0 + sseg * 8];
    __syncthreads();
    bf16x8 af[2], bfr[4];
#pragma unroll
    for (int mi = 0; mi < 2; ++mi)
      af[mi] = *(const bf16x8*)&AsF[(((wr >> 4) + mi) * 64 + (l >> 4) * 16 + (l & 15)) * 8];
#pragma unroll
    for (int ni = 0; ni < 4; ++ni)
      bfr[ni] = *(const bf16x8*)&BsF[(((wc >> 4) + ni) * 64 + (l >> 4) * 16 + (l & 15)) * 8];
#pragma unroll
    for (int mi = 0; mi < 2; ++mi)
#pragma unroll
      for (int ni = 0; ni < 4; ++ni)
        acc[mi][ni] = MFMA16(af[mi], bfr[ni], acc[mi][ni]);
  }
  if (blockIdx.x < 2) {
    bf16* dst = (blockIdx.x == 0) ? Qh : Kh;
#pragma unroll
    for (int ni = 0; ni < 4; ++ni) {
      int cl = wc + ni * 16 + (l & 15);
      int hd = cl >> 4, c16 = cl & 15;
#pragma unroll
      for (int mi = 0; mi < 2; ++mi)
#pragma unroll
        for (int r = 0; r < 4; ++r) {
          int row = bm + wr + mi * 16 + (l >> 4) * 4 + r;
          int b = row / NT_;
          int n = row - b * NT_;
          dst[(((size_t)b * 8 + hd) * NTP + n) * 16 + c16] = (bf16)acc[mi][ni][r];
        }
    }
  } else {
    __syncthreads();
#pragma unroll
    for (int mi = 0; mi < 2; ++mi)
#pragma unroll
      for (int ni = 0; ni < 4; ++ni) {
        int cl = wc + ni * 16 + (l & 15);
        int r0 = wr + mi * 16 + (l >> 4) * 4;
        bf16x4 pk;
#pragma unroll
        for (int r = 0; r < 4; ++r) pk[r] = (bf16)acc[mi][ni][r];
        *(bf16x4*)&Vt2[cl * 68 + r0] = pk;
      }
    __syncthreads();
    int colg = tid >> 4, nl = tid & 15;
#pragma unroll
    for (int ci = 0; ci < 8; ++ci) {
      int lc = colg + ci * 16;
      int hd = lc >> 4, c16 = lc & 15;
#pragma unroll
      for (int ri = 0; ri < 4; ++ri) {
        int lrow = nl + ri * 16;
        int row = bm + lrow;
        int b = row / NT_;
        int n = row - b * NT_;
        Vh[(((size_t)b * 8 + hd) * 16 + c16) * NTP + n] = Vt2[lc * 68 + lrow];
      }
    }
  }
}

// ---------------- fused FF (R8): y = relu(bn1(x)@W1+b1)@W2 + b2 + bn1(x), + stats ----------------
__global__ __launch_bounds__(256) void fffused(
    const bf16* __restrict__ X, const float* __restrict__ mi,
    const bf16* __restrict__ W1t, const float* __restrict__ bias1,
    const bf16* __restrict__ W2t, const float* __restrict__ bias2,
    bf16* __restrict__ Y, float* __restrict__ ps, float* __restrict__ pq) {
  __shared__ bf16 A1[8192];   // 64 x 128, unit-linear
  __shared__ bf16 A2[8192];   // 64 x 128 (ff chunk), unit-linear
  __shared__ bf16 BF[4096];   // 128 x 32 weight staging
  __shared__ float sredS[4][64];
  __shared__ float sredQ[4][64];
  int tid = threadIdx.x;
  int w = tid >> 6, l = tid & 63;
  int bm = blockIdx.x * 64;
#pragma unroll
  for (int it = 0; it < 4; ++it) {
    int idx = it * 256 + tid;
    int row = idx >> 4, seg = idx & 15;
    bf16x8 x = *(const bf16x8*)&X[(size_t)(bm + row) * 128 + seg * 8];
    f32x4 s0 = *(const f32x4*)&mi[seg * 8],       s1 = *(const f32x4*)&mi[seg * 8 + 4];
    f32x4 c0 = *(const f32x4*)&mi[128 + seg * 8], c1 = *(const f32x4*)&mi[128 + seg * 8 + 4];
    bf16x8 y;
#pragma unroll
    for (int i = 0; i < 4; ++i) y[i] = (bf16)__builtin_fmaf((float)x[i], s0[i], c0[i]);
#pragma unroll
    for (int i = 0; i < 4; ++i) y[4 + i] = (bf16)__builtin_fmaf((float)x[4 + i], s1[i], c1[i]);
    *(bf16x8*)&A1[UNIT128(row, seg) * 8] = y;
  }
  int srow = tid >> 2, sseg = tid & 3;
  int uB0 = UNIT(srow, sseg) * 8, uB1 = UNIT(srow + 64, sseg) * 8;
  int wr = (w >> 1) * 32, wc = (w & 1) * 64;
  f32x4 acc2[2][4] = {};

  for (int nc = 0; nc < 4; ++nc) {
    f32x4 acc1[2][4] = {};
    for (int k0 = 0; k0 < 128; k0 += 32) {
      __syncthreads();
      *(bf16x8*)&BF[uB0] = *(const bf16x8*)&W1t[(size_t)(nc * 128 + srow) * 128 + k0 + sseg * 8];
      *(bf16x8*)&BF[uB1] = *(const bf16x8*)&W1t[(size_t)(nc * 128 + srow + 64) * 128 + k0 + sseg * 8];
      __syncthreads();
      bf16x8 af[2], hf[4];
#pragma unroll
      for (int m2 = 0; m2 < 2; ++m2)
        af[m2] = *(const bf16x8*)&BF[((w * 2 + m2) * 64 + (l >> 4) * 16 + (l & 15)) * 8];
#pragma unroll
      for (int ni = 0; ni < 4; ++ni)
        hf[ni] = *(const bf16x8*)&A1[(ni * 256 + ((k0 >> 3) + (l >> 4)) * 16 + (l & 15)) * 8];
#pragma unroll
      for (int m2 = 0; m2 < 2; ++m2)
#pragma unroll
        for (int ni = 0; ni < 4; ++ni)
          acc1[m2][ni] = MFMA16(af[m2], hf[ni], acc1[m2][ni]);
    }
#pragma unroll
    for (int m2 = 0; m2 < 2; ++m2) {
      int ffk0 = w * 32 + m2 * 16 + (l >> 4) * 4;
      int seg = ffk0 >> 3, half = ffk0 & 7;
#pragma unroll
      for (int ni = 0; ni < 4; ++ni) {
        bf16x4 pk;
#pragma unroll
        for (int r = 0; r < 4; ++r) {
          float v = acc1[m2][ni][r] + bias1[nc * 128 + ffk0 + r];
          pk[r] = (bf16)fmaxf(v, 0.f);
        }
        *(bf16x4*)&A2[(ni * 256 + seg * 16 + (l & 15)) * 8 + half] = pk;
      }
    }
    __syncthreads();
    for (int k0 = 0; k0 < 128; k0 += 32) {
      if (k0) __syncthreads();
      *(bf16x8*)&BF[uB0] = *(const bf16x8*)&W2t[(size_t)srow * 512 + nc * 128 + k0 + sseg * 8];
      *(bf16x8*)&BF[uB1] = *(const bf16x8*)&W2t[(size_t)(srow + 64) * 512 + nc * 128 + k0 + sseg * 8];
      __syncthreads();
      bf16x8 a2f[2], b2f[4];
#pragma unroll
      for (int m2 = 0; m2 < 2; ++m2)
        a2f[m2] = *(const bf16x8*)&A2[(((wr >> 4) + m2) * 256 + ((k0 >> 3) + (l >> 4)) * 16 + (l & 15)) * 8];
#pragma unroll
      for (int ni = 0; ni < 4; ++ni)
        b2f[ni] = *(const bf16x8*)&BF[(((wc >> 4) + ni) * 64 + (l >> 4) * 16 + (l & 15)) * 8];
#pragma unroll
      for (int m2 = 0; m2 < 2; ++m2)
#pragma unroll
        for (int ni = 0; ni < 4; ++ni)
          acc2[m2][ni] = MFMA16(a2f[m2], b2f[ni], acc2[m2][ni]);
    }
  }
  float scol[4] = {}, qcol[4] = {};
#pragma unroll
  for (int m2 = 0; m2 < 2; ++m2)
#pragma unroll
    for (int ni = 0; ni < 4; ++ni) {
      int col = wc + ni * 16 + (l & 15);
      float bb = bias2[col];
#pragma unroll
      for (int r = 0; r < 4; ++r) {
        int row = wr + m2 * 16 + (l >> 4) * 4 + r;
        float res = (float)A1[UNIT128(row, col >> 3) * 8 + (col & 7)];
        float v = acc2[m2][ni][r] + bb + res;
        scol[ni] += v; qcol[ni] += v * v;
        Y[(size_t)(bm + row) * 128 + col] = (bf16)v;
      }
    }
#pragma unroll
  for (int ni = 0; ni < 4; ++ni) {
    scol[ni] += __shfl_xor(scol[ni], 16); scol[ni] += __shfl_xor(scol[ni], 32);
    qcol[ni] += __shfl_xor(qcol[ni], 16); qcol[ni] += __shfl_xor(qcol[ni], 32);
  }
  __syncthreads();
  if (l < 16) {
#pragma unroll
    for (int ni = 0; ni < 4; ++ni) {
      sredS[w][ni * 16 + l] = scol[ni];
      sredQ[w][ni * 16 + l] = qcol[ni];
    }
  }
  __syncthreads();
  if (tid < 128) {
    int c = tid, cw = c >> 6, cc = c & 63;
    ps[(size_t)c * 512 + blockIdx.x] = sredS[cw][cc] + sredS[cw + 2][cc];
    pq[(size_t)c * 512 + blockIdx.x] = sredQ[cw][cc] + sredQ[cw + 2][cc];
  }
}

// ---------------- MFMA flash attention V4: register-resident P (cvt_pk + permlane32_swap),
// PV on 32x32x16 with lsum in column 16.  LDS: K (2KB) + V^T (2KB) only.
__global__ __launch_bounds__(256) void mattn(
    const bf16* __restrict__ Qh, const bf16* __restrict__ Kh,
    const bf16* __restrict__ Vh, bf16* __restrict__ ab) {
  __shared__ bf16 KsF[1024];
  __shared__ bf16 VtF[1024];
  int tid = threadIdx.x;
  int w = tid >> 6, l = tid & 63;
  int bh = blockIdx.x;
  int b = bh >> 3, hd = bh & 7;
  const bf16* Qp = Qh + (size_t)bh * NTP * 16;
  const bf16* Kp = Kh + (size_t)bh * NTP * 16;
  const bf16* Vp = Vh + (size_t)bh * 16 * NTP;
  int qbase = blockIdx.y * 128 + w * 32;
  int qrow = qbase + (l & 31); if (qrow >= NT_) qrow = NT_ - 1;
  bf16x8 qf = *(const bf16x8*)&Qp[qrow * 16 + (l >> 5) * 8];

  const float SC = 0.25f * 1.44269504088896f;
  const float MC = 8.0f * SC;
  const f32x16 zz = {0,0,0,0,0,0,0,0,0,0,0,0,0,0,0,0};
  f32x16 oacc = zz;
  bf16x8 ones8, zero8;
#pragma unroll
  for (int i = 0; i < 8; ++i) { ones8[i] = (bf16)1.0f; zero8[i] = (bf16)0.0f; }
  int d31 = l & 31;

  for (int t = 0; t < 16; ++t) {
    int kb = t * 64;
    __syncthreads();
    if (tid < 128) {
      int key = (tid >> 6) * 32 + (tid & 31);
      int h2 = (tid >> 5) & 1;
      int krow = kb + key; if (krow >= NT_) krow = NT_ - 1;
      *(bf16x8*)&KsF[tid * 8] = *(const bf16x8*)&Kp[krow * 16 + h2 * 8];
    } else {
      int u = tid - 128;
      int seg = u >> 4, dim = u & 15;
      *(bf16x8*)&VtF[u * 8] = *(const bf16x8*)&Vp[dim * NTP + kb + seg * 8];
    }
    __syncthreads();

#pragma unroll
    for (int c = 0; c < 2; ++c) {
      bf16x8 kf = *(const bf16x8*)&KsF[(c * 64 + l) * 8];
      f32x16 sv = MFMA32(kf, qf, zz);
      if (kb + 64 > NT_) {
#pragma unroll
        for (int r = 0; r < 16; ++r) {
          int key = kb + c * 32 + (r & 3) + 8 * (r >> 2) + 4 * (l >> 5);
          if (key >= NT_) sv[r] = -1e30f;
        }
      }
#pragma unroll
      for (int r = 0; r < 16; ++r)
        sv[r] = EXP2(__builtin_fmaf(sv[r], SC, -MC));
      // two 16-key chunks -> register P fragments via cvt_pk + permlane32_swap
#pragma unroll
      for (int kk2 = 0; kk2 < 2; ++kk2) {
        int o = kk2 * 8;
        unsigned a0 = pkbf(sv[o + 0], sv[o + 1]);
        unsigned a1 = pkbf(sv[o + 2], sv[o + 3]);
        unsigned b0 = pkbf(sv[o + 4], sv[o + 5]);
        unsigned b1 = pkbf(sv[o + 6], sv[o + 7]);
        auto s01 = __builtin_amdgcn_permlane32_swap(a0, b0, false, false);
        auto s23 = __builtin_amdgcn_permlane32_swap(a1, b1, false, false);
        union { unsigned u[4]; bf16x8 v; } pu;
        pu.u[0] = s01[0]; pu.u[1] = s23[0]; pu.u[2] = s01[1]; pu.u[3] = s23[1];
        int kkG = c * 2 + kk2;                  // 16-key chunk index 0..3
        bf16x8 vb;
        if (d31 < 16)       vb = *(const bf16x8*)&VtF[((kkG * 2 + (l >> 5)) * 16 + d31) * 8];
        else if (d31 == 16) vb = ones8;
        else                vb = zero8;
        oacc = MFMA32(pu.v, vb, oacc);
      }
    }
  }
  // epilogue: col 16 holds lsum per row; broadcast and write
#pragma unroll
  for (int r = 0; r < 16; ++r) {
    float ls = __shfl(oacc[r], (l & 32) + 16);
    int qw = (r & 3) + 8 * (r >> 2) + 4 * (l >> 5);
    int qq = qbase + qw;
    if (d31 < 16 && qq < NT_)
      ab[((size_t)b * NT_ + qq) * 128 + hd * 16 + d31] = (bf16)(oacc[r] / ls);
  }
}

// ---------------- BN finalize (parallel, column-major partials) ----------------
__global__ __launch_bounds__(512) void stats_final(
    const float* __restrict__ ps, const float* __restrict__ pq,
    const float* __restrict__ sc, const float* __restrict__ bi, float* __restrict__ mi) {
  int tid = threadIdx.x;
  int c = tid >> 2, q4 = tid & 3;
  float s = 0.f, q = 0.f;
  for (int p = q4; p < 501; p += 4) { s += ps[c * 512 + p]; q += pq[c * 512 + p]; }
  s += __shfl_xor(s, 1); s += __shfl_xor(s, 2);
  q += __shfl_xor(q, 1); q += __shfl_xor(q, 2);
  if (q4 == 0) {
    float mean = s * (1.f / (float)ROWS);
    float var = q * (1.f / (float)ROWS) - mean * mean;
    float s2 = sc[c] * rsqrtf(var + 1e-5f);
    mi[c] = s2;
    mi[128 + c] = bi[c] - mean * s2;
  }
}

// ---------------- decoder ----------------
__global__ void ge_partial(const bf16* __restrict__ X, const float* __restrict__ mi,
                           float* __restrict__ part) {
  int b = blockIdx.x, ch = blockIdx.y, d = threadIdx.x;
  int n0 = ch * 126, n1 = n0 + 126; if (n1 > NT_) n1 = NT_;
  float sS = mi[d], sB = mi[128 + d];
  float s = 0.f;
  for (int n = n0; n < n1; ++n)
    s += __builtin_fmaf((float)X[((size_t)b * NT_ + n) * D_ + d], sS, sB);
  part[(b * 8 + ch) * D_ + d] = s;
}

__global__ void query_kernel(const float* __restrict__ part, const bf16* __restrict__ X,
                             const float* __restrict__ mi,
                             const float* __restrict__ Wf, const float* __restrict__ Ws,
                             float* __restrict__ qry) {
  __shared__ float sge[128], sh0[128];
  int b = blockIdx.x, d = threadIdx.x;
  float s = 0.f;
#pragma unroll
  for (int ch = 0; ch < 8; ++ch) s += part[(b * 8 + ch) * D_ + d];
  sge[d] = s * (1.f / (float)NT_);
  sh0[d] = __builtin_fmaf((float)X[(size_t)b * NT_ * D_ + d], mi[d], mi[128 + d]);
  __syncthreads();
  float q = 0.f;
  for (int k = 0; k < 128; ++k) q += sge[k] * Wf[k * D_ + d] + sh0[k] * Ws[k * D_ + d];
  qry[b * D_ + d] = q;
}

__global__ __launch_bounds__(256) void glimpse_kernel(
    const bf16* __restrict__ proj, const float* __restrict__ qry,
    const int* __restrict__ mask, float* __restrict__ glimpse) {
  int bid = blockIdx.x; int b = bid >> 3, hd = bid & 7;
  int tid = threadIdx.x;
  __shared__ float sq[16];
  __shared__ float sex[NT_];
  __shared__ float rmax[4];
  __shared__ float wacc[4][17];
  if (tid < 16) sq[tid] = qry[b * 128 + hd * 16 + tid];
  __syncthreads();
  const bf16* P = proj + (size_t)b * NT_ * 384;
  const int* Mk = mask + b * NT_;
  float lmax = -1e30f;
#pragma unroll
  for (int it = 0; it < 4; ++it) {
    int n = tid + it * 256;
    if (n < NT_) {
      float c = NEGV;
      if (!Mk[n]) {
        const bf16* kp = &P[(size_t)n * 384 + hd * 16];
        bf16x8 k0 = *(const bf16x8*)kp, k1 = *(const bf16x8*)(kp + 8);
        float d = 0.f;
#pragma unroll
        for (int i = 0; i < 8; ++i) d += sq[i] * (float)k0[i] + sq[8 + i] * (float)k1[i];
        c = d * 0.25f;
      }
      sex[n] = c;
      lmax = fmaxf(lmax, c);
    }
  }
#pragma unroll
  for (int o = 32; o > 0; o >>= 1) lmax = fmaxf(lmax, __shfl_xor(lmax, o));
  if ((tid & 63) == 0) rmax[tid >> 6] = lmax;
  __syncthreads();
  float mx = fmaxf(fmaxf(rmax[0], rmax[1]), fmaxf(rmax[2], rmax[3]));
  float acc[16];
#pragma unroll
  for (int i = 0; i < 16; ++i) acc[i] = 0.f;
  float lsum = 0.f;
#pragma unroll
  for (int it = 0; it < 4; ++it) {
    int n = tid + it * 256;
    if (n < NT_) {
      float e = __expf(sex[n] - mx);
      lsum += e;
      const bf16* vp = &P[(size_t)n * 384 + 128 + hd * 16];
      bf16x8 v0 = *(const bf16x8*)vp, v1 = *(const bf16x8*)(vp + 8);
#pragma unroll
      for (int i = 0; i < 8; ++i) { acc[i] += e * (float)v0[i]; acc[8 + i] += e * (float)v1[i]; }
    }
  }
#pragma unroll
  for (int o = 32; o > 0; o >>= 1) {
    lsum += __shfl_xor(lsum, o);
#pragma unroll
    for (int i = 0; i < 16; ++i) acc[i] += __shfl_xor(acc[i], o);
  }
  if ((tid & 63) == 0) {
    wacc[tid >> 6][16] = lsum;
#pragma unroll
    for (int i = 0; i < 16; ++i) wacc[tid >> 6][i] = acc[i];
  }
  __syncthreads();
  if (tid < 16) {
    float a = wacc[0][tid] + wacc[1][tid] + wacc[2][tid] + wacc[3][tid];
    float L = wacc[0][16] + wacc[1][16] + wacc[2][16] + wacc[3][16];
    glimpse[b * 128 + hd * 16 + tid] = a / L;
  }
}

__global__ void g2_kernel(const float* __restrict__ glimpse, const float* __restrict__ Wout,
                          float* __restrict__ g2) {
  __shared__ float sg[128];
  int b = blockIdx.x, d = threadIdx.x;
  sg[d] = glimpse[b * 128 + d];
  __syncthreads();
  float s = 0.f;
  for (int k = 0; k < 128; ++k) s += sg[k] * Wout[k * 128 + d];
  g2[b * 128 + d] = s;
}

__global__ __launch_bounds__(256) void logits_kernel(
    const bf16* __restrict__ proj, const float* __restrict__ g2,
    const int* __restrict__ mask, float* __restrict__ logits) {
  int b = blockIdx.y;
  int n = blockIdx.x * 256 + threadIdx.x;
  __shared__ float sg[128];
  if (threadIdx.x < 128) sg[threadIdx.x] = g2[b * 128 + threadIdx.x];
  __syncthreads();
  if (n >= NT_) return;
  const bf16* kp = &proj[((size_t)b * NT_ + n) * 384 + 256];
  float d = 0.f;
#pragma unroll
  for (int j = 0; j < 16; ++j) {
    bf16x8 v = *(const bf16x8*)&kp[j * 8];
#pragma unroll
    for (int i = 0; i < 8; ++i) d += sg[j * 8 + i] * (float)v[i];
  }
  d = 10.f * tanhf(d * 0.088388347648318447f);
  logits[b * NT_ + n] = mask[b * NT_ + n] ? NEGV : d;
}

__global__ __launch_bounds__(256) void lsm_kernel(const float* __restrict__ logits, float* __restrict__ out) {
  int b = blockIdx.x, tid = threadIdx.x;
  __shared__ float red[256];
  float mx = -1e30f;
  for (int n = tid; n < NT_; n += 256) mx = fmaxf(mx, logits[b * NT_ + n]);
  red[tid] = mx; __syncthreads();
  for (int s = 128; s > 0; s >>= 1) { if (tid < s) red[tid] = fmaxf(red[tid], red[tid + s]); __syncthreads(); }
  mx = red[0]; __syncthreads();
  float sm = 0.f;
  for (int n = tid; n < NT_; n += 256) sm += __expf(logits[b * NT_ + n] - mx);
  red[tid] = sm; __syncthreads();
  for (int s = 128; s > 0; s >>= 1) { if (tid < s) red[tid] += red[tid + s]; __syncthreads(); }
  float lse = mx + logf(red[0]);
  for (int n = tid; n < NT_; n += 256) out[(size_t)b * NT_ + n] = logits[b * NT_ + n] - lse;
}

// ---------------- launcher ----------------
extern "C" void kernel_launch(void* const* d_in, const int* in_sizes, int n_in,
                              void* d_out, int out_size, void* d_ws, size_t ws_size,
                              hipStream_t stream) {
  const float* depot        = (const float*)d_in[0];
  const float* loc          = (const float*)d_in[1];
  const float* demand       = (const float*)d_in[2];
  const int*   mask         = (const int*)d_in[3];
  const float* W_init_node  = (const float*)d_in[4];
  const float* b_init_node  = (const float*)d_in[5];
  const float* W_init_depot = (const float*)d_in[6];
  const float* b_init_depot = (const float*)d_in[7];
  const float* enc_Wqkv     = (const float*)d_in[8];
  const float* enc_Wo       = (const float*)d_in[9];
  const float* enc_W1       = (const float*)d_in[10];
  const float* enc_b1       = (const float*)d_in[11];
  const float* enc_W2       = (const float*)d_in[12];
  const float* enc_b2       = (const float*)d_in[13];
  const float* bn1_s        = (const float*)d_in[14];
  const float* bn1_b        = (const float*)d_in[15];
  const float* bn2_s        = (const float*)d_in[16];
  const float* bn2_b        = (const float*)d_in[17];
  const float* W_proj       = (const float*)d_in[18];
  const float* W_fixed      = (const float*)d_in[19];
  const float* W_step       = (const float*)d_in[20];
  const float* W_out        = (const float*)d_in[21];
  float* out = (float*)d_out;

  char* base = (char*)d_ws;
  bf16*  hb0   = (bf16*)(base);                        // 8,208,384
  bf16*  ab    = (bf16*)(base + 8208384);              // 8,208,384
  bf16*  Qh    = (bf16*)(base + 16416768);             // 8,388,608 [bh][NTP][16]
  bf16*  Kh    = (bf16*)(base + 24805376);             // 8,388,608
  bf16*  Vh    = (bf16*)(base + 33193984);             // 8,388,608 [bh*16+c16][NTP]
  bf16*  xb1   = Qh;                                   // alias (post-mattn lifetime)
  bf16*  xb2   = (bf16*)(base + 41582592);             // 8,208,384
  bf16*  projb = (bf16*)(base + 49790976);             // 24,625,152
  bf16*  wb    = (bf16*)(base + 74416128);             // 884,736
  float* ps    = (float*)(base + 75300864);            // 262,144 [128 col][512]
  float* pq    = (float*)(base + 75563008);            // 262,144
  float* mi1   = (float*)(base + 75825152);            // 1,024
  float* mi2   = (float*)(base + 75826176);            // 1,024
  float* qry   = (float*)(base + 75827200);            // 16,384
  float* glim  = (float*)(base + 75843584);            // 16,384
  float* g2    = (float*)(base + 75859968);            // 16,384
  float* gep   = ps;                                   // decoder reuse
  float* logit = pq;                                   // decoder reuse

  bf16* wt_qkv  = wb;
  bf16* wt_wo   = wb + SZ_QKV;
  bf16* wt_w1   = wb + SZ_QKV + SZ_WO;
  bf16* wt_w2   = wb + SZ_QKV + SZ_WO + SZ_W1;
  bf16* wt_proj = wb + SZ_QKV + SZ_WO + SZ_W1 + SZ_W2;

  prep_w<<<1728, 256, 0, stream>>>(enc_Wqkv, enc_Wo, enc_W1, enc_W2, W_proj, wb);
  init_kernel<<<(ROWS * D_ + 255) / 256, 256, 0, stream>>>(
      depot, loc, demand, W_init_node, b_init_node, W_init_depot, b_init_depot, hb0);

  for (int l = 0; l < 2; ++l) {
    const bf16* hin = (l == 0) ? hb0 : xb2;
    if (l == 0)
      mgemm_qkv<false><<<dim3(3, 501), 256, 0, stream>>>(hin, wt_qkv, nullptr, Qh, Kh, Vh);
    else
      mgemm_qkv<true><<<dim3(3, 501), 256, 0, stream>>>(hin, wt_qkv + (size_t)384 * 128, mi2, Qh, Kh, Vh);
    mattn<<<dim3(256, 8), 256, 0, stream>>>(Qh, Kh, Vh, ab);
    if (l == 0)
      mgemm<128, 128, false, false, true, true, false, false><<<dim3(1, 501), 256, 0, stream>>>(
          ab, wt_wo, nullptr, hin, xb1, ps, pq, nullptr, nullptr);
    else
      mgemm<128, 128, false, false, true, true, false, true><<<dim3(1, 501), 256, 0, stream>>>(
          ab, wt_wo + (size_t)128 * 128, nullptr, hin, xb1, ps, pq, nullptr, mi2);
    stats_final<<<1, 512, 0, stream>>>(ps, pq, bn1_s + l * D_, bn1_b + l * D_, mi1);
    fffused<<<501, 256, 0, stream>>>(
        xb1, mi1, wt_w1 + (size_t)l * 512 * 128, enc_b1 + (size_t)l * FF_,
        wt_w2 + (size_t)l * 128 * 512, enc_b2 + (size_t)l * D_, xb2, ps, pq);
    stats_final<<<1, 512, 0, stream>>>(ps, pq, bn2_s + l * D_, bn2_b + l * D_, mi2);
  }

  // decoder
  mgemm<384, 128, false, false, false, false, true, false><<<dim3(3, 501), 256, 0, stream>>>(
      xb2, wt_proj, nullptr, nullptr, projb, nullptr, nullptr, mi2, nullptr);
  ge_partial<<<dim3(32, 8), 128, 0, stream>>>(xb2, mi2, gep);
  query_kernel<<<32, 128, 0, stream>>>(gep, xb2, mi2, W_fixed, W_step, qry);
  glimpse_kernel<<<256, 256, 0, stream>>>(projb, qry, mask, glim);
  g2_kernel<<<32, 128, 0, stream>>>(glim, W_out, g2);
  logits_kernel<<<dim3(4, 32), 256, 0, stream>>>(projb, g2, mask, logit);
  lsm_kernel<<<32, 256, 0, stream>>>(logit, out);
}

// Round 11
// 380.845 us; speedup vs baseline: 1.0525x; 1.0180x over previous
//
#include <hip/hip_runtime.h>

#define B_   32
#define NT_  1002
#define D_   128
#define H_   8
#define FF_  512
#define ROWS (B_ * NT_)          // 32064 = 501*64
#define NEGV (-1e9f)
#define NTP  1024                // padded rows per (b,head)

typedef __bf16 bf16;
typedef __bf16 bf16x8 __attribute__((ext_vector_type(8)));
typedef __bf16 bf16x4 __attribute__((ext_vector_type(4)));
typedef float  f32x4  __attribute__((ext_vector_type(4)));
typedef float  f32x16 __attribute__((ext_vector_type(16)));

#if __has_builtin(__builtin_amdgcn_exp2f)
#define EXP2(x) __builtin_amdgcn_exp2f(x)
#else
#define EXP2(x) exp2f(x)
#endif

#define MFMA16(a, b, c) __builtin_amdgcn_mfma_f32_16x16x32_bf16(a, b, c, 0, 0, 0)
#define MFMA32(a, b, c) __builtin_amdgcn_mfma_f32_32x32x16_bf16(a, b, c, 0, 0, 0)

// async global->LDS, 16B per lane; dest must be (wave-uniform base) + lane*16
__device__ __forceinline__ void gl_lds16(const bf16* g, bf16* l) {
  __builtin_amdgcn_global_load_lds(
      (const __attribute__((address_space(1))) unsigned int*)(uintptr_t)g,
      (__attribute__((address_space(3))) unsigned int*)(uintptr_t)l,
      16, 0, 0);
}

// unit-linear LDS tile addressing: 16B unit for (row, 8-elem k-seg), 32-k tiles
__device__ __forceinline__ int UNIT(int row, int seg) {
  return (row >> 4) * 64 + seg * 16 + (row & 15);
}
// 128-k tiles (16 segs)
__device__ __forceinline__ int UNIT128(int row, int seg) {
  return (row >> 4) * 256 + seg * 16 + (row & 15);
}

// ---------------- weight prep: transpose + convert to bf16 [n][k] ----------------
#define SZ_QKV (2*384*128)
#define SZ_WO  (2*128*128)
#define SZ_W1  (2*512*128)
#define SZ_W2  (2*128*512)
#define SZ_PROJ (384*128)

__global__ __launch_bounds__(256) void prep_w(
    const float* __restrict__ qkv, const float* __restrict__ wo, const float* __restrict__ w1,
    const float* __restrict__ w2, const float* __restrict__ proj, bf16* __restrict__ out) {
  int i = blockIdx.x * 256 + threadIdx.x;
  int j = i;
  float v;
  if (j < SZ_QKV) {
    int l = j / 49152, r = j % 49152; int n = r >> 7, k = r & 127;
    v = qkv[((size_t)l * 128 + k) * 384 + n];
  } else {
    j -= SZ_QKV;
    if (j < SZ_WO) {
      int l = j >> 14, r = j & 16383; int n = r >> 7, k = r & 127;
      v = wo[((size_t)l * 128 + k) * 128 + n];
    } else {
      j -= SZ_WO;
      if (j < SZ_W1) {
        int l = j >> 16, r = j & 65535; int n = r >> 7, k = r & 127;
        v = w1[((size_t)l * 128 + k) * 512 + n];
      } else {
        j -= SZ_W1;
        if (j < SZ_W2) {
          int l = j >> 16, r = j & 65535; int n = r >> 9, k = r & 511;
          v = w2[((size_t)l * 512 + k) * 128 + n];
        } else {
          j -= SZ_W2;
          int n = j >> 7, k = j & 127;
          v = proj[(size_t)k * 384 + n];
        }
      }
    }
  }
  out[i] = (bf16)v;
}

// ---------------- init embeddings (bf16) ----------------
__global__ __launch_bounds__(256) void init_kernel(
    const float* __restrict__ depot, const float* __restrict__ loc, const float* __restrict__ demand,
    const float* __restrict__ Wn, const float* __restrict__ bn_, const float* __restrict__ Wd,
    const float* __restrict__ bd, bf16* __restrict__ hb) {
  int idx = blockIdx.x * 256 + threadIdx.x;
  if (idx >= ROWS * D_) return;
  int c = idx & 127;
  int row = idx >> 7;
  int b = row / NT_;
  int n = row - b * NT_;
  float v;
  if (n < 2) {
    const float* dp = depot + (b * 2 + n) * 2;
    v = dp[0] * Wd[c] + dp[1] * Wd[D_ + c] + bd[c];
  } else {
    int i = n - 2;
    const float* lp = loc + ((size_t)b * 1000 + i) * 2;
    v = lp[0] * Wn[c] + lp[1] * Wn[D_ + c] + demand[b * 1000 + i] * Wn[2 * D_ + c] + bn_[c];
  }
  hb[idx] = (bf16)v;
}

// ---------------- MFMA GEMM (R8 + async staging): tile 64(M) x 128(N) ----------------
// A [ROWS][K_] bf16, Wt [N][K] bf16; STATS partials column-major ps[(bn+c)*512 + by]
template<int N_, int K_, bool BIAS, bool RELU, bool RES, bool STATS, bool BNA, bool BNR>
__global__ __launch_bounds__(256) void mgemm(
    const bf16* __restrict__ A, const bf16* __restrict__ Wt,
    const float* __restrict__ bias, const bf16* __restrict__ R, bf16* __restrict__ Cout,
    float* __restrict__ ps, float* __restrict__ pq,
    const float* __restrict__ miA, const float* __restrict__ miR) {
  __shared__ bf16 AsF[2048];
  __shared__ bf16 BsF[4096];
  __shared__ float sredS[4][64];
  __shared__ float sredQ[4][64];
  int tid = threadIdx.x;
  int w = tid >> 6, l = tid & 63;
  int bm = blockIdx.y * 64, bn = blockIdx.x * 128;
  int wr = (w >> 1) * 32, wc = (w & 1) * 64;
  f32x4 acc[2][4] = {};
  // DMA mapping: unit w*64+l  <->  row = w*16+(l&15), seg = (l>>4)&3
  int drow = (w << 4) + (l & 15), dseg = (l >> 4) & 3;
  // reg-staging mapping (BNA path)
  int srow = tid >> 2, sseg = tid & 3;
  int uA = UNIT(srow, sseg) * 8;
  for (int k0 = 0; k0 < K_; k0 += 32) {
    __syncthreads();
    if (BNA) {
      bf16x8 x = *(const bf16x8*)&A[(size_t)(bm + srow) * K_ + k0 + sseg * 8];
      int kc = k0 + sseg * 8;
      f32x4 s0 = *(const f32x4*)&miA[kc],       s1 = *(const f32x4*)&miA[kc + 4];
      f32x4 c0 = *(const f32x4*)&miA[128 + kc], c1 = *(const f32x4*)&miA[128 + kc + 4];
      bf16x8 y;
#pragma unroll
      for (int i = 0; i < 4; ++i) y[i] = (bf16)__builtin_fmaf((float)x[i], s0[i], c0[i]);
#pragma unroll
      for (int i = 0; i < 4; ++i) y[4 + i] = (bf16)__builtin_fmaf((float)x[4 + i], s1[i], c1[i]);
      *(bf16x8*)&AsF[uA] = y;
    } else {
      gl_lds16(&A[(size_t)(bm + drow) * K_ + k0 + dseg * 8], &AsF[(w * 64 + l) * 8]);
    }
    gl_lds16(&Wt[(size_t)(bn + drow) * K_ + k0 + dseg * 8], &BsF[(w * 64 + l) * 8]);
    gl_lds16(&Wt[(size_t)(bn + 64 + drow) * K_ + k0 + dseg * 8], &BsF[(256 + w * 64 + l) * 8]);
    __syncthreads();
    bf16x8 af[2], bfr[4];
#pragma unroll
    for (int mi = 0; mi < 2; ++mi)
      af[mi] = *(const bf16x8*)&AsF[(((wr >> 4) + mi) * 64 + (l >> 4) * 16 + (l & 15)) * 8];
#pragma unroll
    for (int ni = 0; ni < 4; ++ni)
      bfr[ni] = *(const bf16x8*)&BsF[(((wc >> 4) + ni) * 64 + (l >> 4) * 16 + (l & 15)) * 8];
#pragma unroll
    for (int mi = 0; mi < 2; ++mi)
#pragma unroll
      for (int ni = 0; ni < 4; ++ni)
        acc[mi][ni] = MFMA16(af[mi], bfr[ni], acc[mi][ni]);
  }
  float scol[4] = {}, qcol[4] = {};
#pragma unroll
  for (int mi = 0; mi < 2; ++mi)
#pragma unroll
    for (int ni = 0; ni < 4; ++ni) {
      int col = bn + wc + ni * 16 + (l & 15);
      float rs = 1.f, rb = 0.f;
      if (RES && BNR) { rs = miR[col]; rb = miR[128 + col]; }
#pragma unroll
      for (int r = 0; r < 4; ++r) {
        int row = bm + wr + mi * 16 + (l >> 4) * 4 + r;
        float v = acc[mi][ni][r];
        if (BIAS) v += bias[col];
        if (RELU) v = fmaxf(v, 0.f);
        if (RES) {
          float x = (float)R[(size_t)row * N_ + col];
          v += BNR ? __builtin_fmaf(x, rs, rb) : x;
        }
        if (STATS) { scol[ni] += v; qcol[ni] += v * v; }
        Cout[(size_t)row * N_ + col] = (bf16)v;
      }
    }
  if (STATS) {
#pragma unroll
    for (int ni = 0; ni < 4; ++ni) {
      scol[ni] += __shfl_xor(scol[ni], 16); scol[ni] += __shfl_xor(scol[ni], 32);
      qcol[ni] += __shfl_xor(qcol[ni], 16); qcol[ni] += __shfl_xor(qcol[ni], 32);
    }
    __syncthreads();
    if (l < 16) {
#pragma unroll
      for (int ni = 0; ni < 4; ++ni) {
        sredS[w][ni * 16 + l] = scol[ni];
        sredQ[w][ni * 16 + l] = qcol[ni];
      }
    }
    __syncthreads();
    if (tid < 128) {
      int c = tid, cw = c >> 6, cc = c & 63;
      ps[(size_t)(bn + c) * 512 + blockIdx.y] = sredS[cw][cc] + sredS[cw + 2][cc];
      pq[(size_t)(bn + c) * 512 + blockIdx.y] = sredQ[cw][cc] + sredQ[cw + 2][cc];
    }
  }
}

// ---------------- QKV GEMM (R8 + async staging): x=0 -> Q, x=1 -> K, x=2 -> V(transposed) ----------------
template<bool BNA>
__global__ __launch_bounds__(256) void mgemm_qkv(
    const bf16* __restrict__ A, const bf16* __restrict__ Wt, const float* __restrict__ miA,
    bf16* __restrict__ Qh, bf16* __restrict__ Kh, bf16* __restrict__ Vh) {
  __shared__ bf16 smem[128 * 68];     // As(2048) + Bs(4096) | Vt2(128x68)
  bf16* AsF = smem;
  bf16* BsF = smem + 2048;
  bf16* Vt2 = smem;
  int tid = threadIdx.x;
  int w = tid >> 6, l = tid & 63;
  int bm = blockIdx.y * 64, bn = blockIdx.x * 128;
  int wr = (w >> 1) * 32, wc = (w & 1) * 64;
  f32x4 acc[2][4] = {};
  int drow = (w << 4) + (l & 15), dseg = (l >> 4) & 3;
  int srow = tid >> 2, sseg = tid & 3;
  int uA = UNIT(srow, sseg) * 8;
  for (int k0 = 0; k0 < 128; k0 += 32) {
    __syncthreads();
    if (BNA) {
      bf16x8 x = *(const bf16x8*)&A[(size_t)(bm + srow) * 128 + k0 + sseg * 8];
      int kc = k0 + sseg * 8;
      f32x4 s0 = *(const f32x4*)&miA[kc],       s1 = *(const f32x4*)&miA[kc + 4];
      f32x4 c0 = *(const f32x4*)&miA[128 + kc], c1 = *(const f32x4*)&miA[128 + kc + 4];
      bf16x8 y;
#pragma unroll
      for (int i = 0; i < 4; ++i) y[i] = (bf16)__builtin_fmaf((float)x[i], s0[i], c0[i]);
#pragma unroll
      for (int i = 0; i < 4; ++i) y[4 + i] = (bf16)__builtin_fmaf((float)x[4 + i], s1[i], c1[i]);
      *(bf16x8*)&AsF[uA] = y;
    } else {
      gl_lds16(&A[(size_t)(bm + drow) * 128 + k0 + dseg * 8], &AsF[(w * 64 + l) * 8]);
    }
    gl_lds16(&Wt[(size_t)(bn + drow) * 128 + k0 + dseg * 8], &BsF[(w * 64 + l) * 8]);
    gl_lds16(&Wt[(size_t)(bn + 64 + drow) * 128 + k0 + dseg * 8], &BsF[(256 + w * 64 + l) * 8]);
    __syncthreads();
    bf16x8 af[2], bfr[4];
#pragma unroll
    for (int mi = 0; mi < 2; ++mi)
      af[mi] = *(const bf16x8*)&AsF[(((wr >> 4) + mi) * 64 + (l >> 4) * 16 + (l & 15)) * 8];
#pragma unroll
    for (int ni = 0; ni < 4; ++ni)
      bfr[ni] = *(const bf16x8*)&BsF[(((wc >> 4) + ni) * 64 + (l >> 4) * 16 + (l & 15)) * 8];
#pragma unroll
    for (int mi = 0; mi < 2; ++mi)
#pragma unroll
      for (int ni = 0; ni < 4; ++ni)
        acc[mi][ni] = MFMA16(af[mi], bfr[ni], acc[mi][ni]);
  }
  if (blockIdx.x < 2) {
    bf16* dst = (blockIdx.x == 0) ? Qh : Kh;
#pragma unroll
    for (int ni = 0; ni < 4; ++ni) {
      int cl = wc + ni * 16 + (l & 15);
      int hd = cl >> 4, c16 = cl & 15;
#pragma unroll
      for (int mi = 0; mi < 2; ++mi)
#pragma unroll
        for (int r = 0; r < 4; ++r) {
          int row = bm + wr + mi * 16 + (l >> 4) * 4 + r;
          int b = row / NT_;
          int n = row - b * NT_;
          dst[(((size_t)b * 8 + hd) * NTP + n) * 16 + c16] = (bf16)acc[mi][ni][r];
        }
    }
  } else {
    __syncthreads();
#pragma unroll
    for (int mi = 0; mi < 2; ++mi)
#pragma unroll
      for (int ni = 0; ni < 4; ++ni) {
        int cl = wc + ni * 16 + (l & 15);
        int r0 = wr + mi * 16 + (l >> 4) * 4;
        bf16x4 pk;
#pragma unroll
        for (int r = 0; r < 4; ++r) pk[r] = (bf16)acc[mi][ni][r];
        *(bf16x4*)&Vt2[cl * 68 + r0] = pk;
      }
    __syncthreads();
    int colg = tid >> 4, nl = tid & 15;
#pragma unroll
    for (int ci = 0; ci < 8; ++ci) {
      int lc = colg + ci * 16;
      int hd = lc >> 4, c16 = lc & 15;
#pragma unroll
      for (int ri = 0; ri < 4; ++ri) {
        int lrow = nl + ri * 16;
        int row = bm + lrow;
        int b = row / NT_;
        int n = row - b * NT_;
        Vh[(((size_t)b * 8 + hd) * 16 + c16) * NTP + n] = Vt2[lc * 68 + lrow];
      }
    }
  }
}

// ---------------- fused FF (R8 + async weight staging) ----------------
__global__ __launch_bounds__(256) void fffused(
    const bf16* __restrict__ X, const float* __restrict__ mi,
    const bf16* __restrict__ W1t, const float* __restrict__ bias1,
    const bf16* __restrict__ W2t, const float* __restrict__ bias2,
    bf16* __restrict__ Y, float* __restrict__ ps, float* __restrict__ pq) {
  __shared__ bf16 A1[8192];   // 64 x 128, unit-linear
  __shared__ bf16 A2[8192];   // 64 x 128 (ff chunk), unit-linear
  __shared__ bf16 BF[4096];   // 128 x 32 weight staging
  __shared__ float sredS[4][64];
  __shared__ float sredQ[4][64];
  int tid = threadIdx.x;
  int w = tid >> 6, l = tid & 63;
  int bm = blockIdx.x * 64;
#pragma unroll
  for (int it = 0; it < 4; ++it) {
    int idx = it * 256 + tid;
    int row = idx >> 4, seg = idx & 15;
    bf16x8 x = *(const bf16x8*)&X[(size_t)(bm + row) * 128 + seg * 8];
    f32x4 s0 = *(const f32x4*)&mi[seg * 8],       s1 = *(const f32x4*)&mi[seg * 8 + 4];
    f32x4 c0 = *(const f32x4*)&mi[128 + seg * 8], c1 = *(const f32x4*)&mi[128 + seg * 8 + 4];
    bf16x8 y;
#pragma unroll
    for (int i = 0; i < 4; ++i) y[i] = (bf16)__builtin_fmaf((float)x[i], s0[i], c0[i]);
#pragma unroll
    for (int i = 0; i < 4; ++i) y[4 + i] = (bf16)__builtin_fmaf((float)x[4 + i], s1[i], c1[i]);
    *(bf16x8*)&A1[UNIT128(row, seg) * 8] = y;
  }
  int drow = (w << 4) + (l & 15), dseg = (l >> 4) & 3;
  int wr = (w >> 1) * 32, wc = (w & 1) * 64;
  f32x4 acc2[2][4] = {};

  for (int nc = 0; nc < 4; ++nc) {
    f32x4 acc1[2][4] = {};
    for (int k0 = 0; k0 < 128; k0 += 32) {
      __syncthreads();
      gl_lds16(&W1t[(size_t)(nc * 128 + drow) * 128 + k0 + dseg * 8], &BF[(w * 64 + l) * 8]);
      gl_lds16(&W1t[(size_t)(nc * 128 + 64 + drow) * 128 + k0 + dseg * 8], &BF[(256 + w * 64 + l) * 8]);
      __syncthreads();
      bf16x8 af[2], hf[4];
#pragma unroll
      for (int m2 = 0; m2 < 2; ++m2)
        af[m2] = *(const bf16x8*)&BF[((w * 2 + m2) * 64 + (l >> 4) * 16 + (l & 15)) * 8];
#pragma unroll
      for (int ni = 0; ni < 4; ++ni)
        hf[ni] = *(const bf16x8*)&A1[(ni * 256 + ((k0 >> 3) + (l >> 4)) * 16 + (l & 15)) * 8];
#pragma unroll
      for (int m2 = 0; m2 < 2; ++m2)
#pragma unroll
        for (int ni = 0; ni < 4; ++ni)
          acc1[m2][ni] = MFMA16(af[m2], hf[ni], acc1[m2][ni]);
    }
#pragma unroll
    for (int m2 = 0; m2 < 2; ++m2) {
      int ffk0 = w * 32 + m2 * 16 + (l >> 4) * 4;
      int seg = ffk0 >> 3, half = ffk0 & 7;
#pragma unroll
      for (int ni = 0; ni < 4; ++ni) {
        bf16x4 pk;
#pragma unroll
        for (int r = 0; r < 4; ++r) {
          float v = acc1[m2][ni][r] + bias1[nc * 128 + ffk0 + r];
          pk[r] = (bf16)fmaxf(v, 0.f);
        }
        *(bf16x4*)&A2[(ni * 256 + seg * 16 + (l & 15)) * 8 + half] = pk;
      }
    }
    __syncthreads();
    for (int k0 = 0; k0 < 128; k0 += 32) {
      if (k0) __syncthreads();
      gl_lds16(&W2t[(size_t)drow * 512 + nc * 128 + k0 + dseg * 8], &BF[(w * 64 + l) * 8]);
      gl_lds16(&W2t[(size_t)(64 + drow) * 512 + nc * 128 + k0 + dseg * 8], &BF[(256 + w * 64 + l) * 8]);
      __syncthreads();
      bf16x8 a2f[2], b2f[4];
#pragma unroll
      for (int m2 = 0; m2 < 2; ++m2)
        a2f[m2] = *(const bf16x8*)&A2[(((wr >> 4) + m2) * 256 + ((k0 >> 3) + (l >> 4)) * 16 + (l & 15)) * 8];
#pragma unroll
      for (int ni = 0; ni < 4; ++ni)
        b2f[ni] = *(const bf16x8*)&BF[(((wc >> 4) + ni) * 64 + (l >> 4) * 16 + (l & 15)) * 8];
#pragma unroll
      for (int m2 = 0; m2 < 2; ++m2)
#pragma unroll
        for (int ni = 0; ni < 4; ++ni)
          acc2[m2][ni] = MFMA16(a2f[m2], b2f[ni], acc2[m2][ni]);
    }
  }
  float scol[4] = {}, qcol[4] = {};
#pragma unroll
  for (int m2 = 0; m2 < 2; ++m2)
#pragma unroll
    for (int ni = 0; ni < 4; ++ni) {
      int col = wc + ni * 16 + (l & 15);
      float bb = bias2[col];
#pragma unroll
      for (int r = 0; r < 4; ++r) {
        int row = wr + m2 * 16 + (l >> 4) * 4 + r;
        float res = (float)A1[UNIT128(row, col >> 3) * 8 + (col & 7)];
        float v = acc2[m2][ni][r] + bb + res;
        scol[ni] += v; qcol[ni] += v * v;
        Y[(size_t)(bm + row) * 128 + col] = (bf16)v;
      }
    }
#pragma unroll
  for (int ni = 0; ni < 4; ++ni) {
    scol[ni] += __shfl_xor(scol[ni], 16); scol[ni] += __shfl_xor(scol[ni], 32);
    qcol[ni] += __shfl_xor(qcol[ni], 16); qcol[ni] += __shfl_xor(qcol[ni], 32);
  }
  __syncthreads();
  if (l < 16) {
#pragma unroll
    for (int ni = 0; ni < 4; ++ni) {
      sredS[w][ni * 16 + l] = scol[ni];
      sredQ[w][ni * 16 + l] = qcol[ni];
    }
  }
  __syncthreads();
  if (tid < 128) {
    int c = tid, cw = c >> 6, cc = c & 63;
    ps[(size_t)c * 512 + blockIdx.x] = sredS[cw][cc] + sredS[cw + 2][cc];
    pq[(size_t)c * 512 + blockIdx.x] = sredQ[cw][cc] + sredQ[cw + 2][cc];
  }
}

// ---------------- MFMA flash attention V3 (58us) + async K/V staging ----------------
__global__ __launch_bounds__(256) void mattn(
    const bf16* __restrict__ Qh, const bf16* __restrict__ Kh,
    const bf16* __restrict__ Vh, bf16* __restrict__ ab) {
  __shared__ bf16 KsF[1024];
  __shared__ bf16 VtF[1024];
  __shared__ bf16 PsF[4][2048];
  int tid = threadIdx.x;
  int w = tid >> 6, l = tid & 63;
  int bh = blockIdx.x;
  int b = bh >> 3, hd = bh & 7;
  const bf16* Qp = Qh + (size_t)bh * NTP * 16;
  const bf16* Kp = Kh + (size_t)bh * NTP * 16;
  const bf16* Vp = Vh + (size_t)bh * 16 * NTP;
  int qbase = blockIdx.y * 128 + w * 32;
  int qrow = qbase + (l & 31); if (qrow >= NT_) qrow = NT_ - 1;
  bf16x8 qf = *(const bf16x8*)&Qp[qrow * 16 + (l >> 5) * 8];

  const float SC = 0.25f * 1.44269504088896f;
  const float MC = 8.0f * SC;
  f32x4 oacc[2] = {};
  f32x4 lacc[2] = {};
  bf16x8 ones;
#pragma unroll
  for (int i = 0; i < 8; ++i) ones[i] = (bf16)1.0f;
  const f32x16 zz = {0,0,0,0,0,0,0,0,0,0,0,0,0,0,0,0};

  for (int t = 0; t < 16; ++t) {
    int kb = t * 64;
    __syncthreads();
    if (tid < 128) {
      int key = (tid >> 6) * 32 + (tid & 31);
      int h2 = (tid >> 5) & 1;
      int krow = kb + key; if (krow >= NT_) krow = NT_ - 1;
      gl_lds16(&Kp[krow * 16 + h2 * 8], &KsF[tid * 8]);
    } else {
      int u = tid - 128;
      int seg = u >> 4, dim = u & 15;
      gl_lds16(&Vp[dim * NTP + kb + seg * 8], &VtF[u * 8]);
    }
    __syncthreads();

    f32x16 sv[2];
#pragma unroll
    for (int c = 0; c < 2; ++c) {
      bf16x8 kf = *(const bf16x8*)&KsF[(c * 64 + l) * 8];
      sv[c] = MFMA32(kf, qf, zz);
    }
    if (kb + 64 > NT_) {
#pragma unroll
      for (int c = 0; c < 2; ++c)
#pragma unroll
        for (int r = 0; r < 16; ++r) {
          int key = kb + c * 32 + (r & 3) + 8 * (r >> 2) + 4 * (l >> 5);
          if (key >= NT_) sv[c][r] = -1e30f;
        }
    }
#pragma unroll
    for (int c = 0; c < 2; ++c)
#pragma unroll
      for (int r = 0; r < 16; ++r)
        sv[c][r] = EXP2(__builtin_fmaf(sv[c][r], SC, -MC));
    {
      int q = l & 31;
      int qh4 = q >> 4, ql = q & 15, half = (l >> 5) * 4;
#pragma unroll
      for (int c = 0; c < 2; ++c)
#pragma unroll
        for (int g2 = 0; g2 < 4; ++g2) {
          bf16x4 pk;
#pragma unroll
          for (int i = 0; i < 4; ++i) pk[i] = (bf16)sv[c][g2 * 4 + i];
          int unit = (c * 2 + qh4) * 64 + g2 * 16 + ql;
          *(bf16x4*)&PsF[w][unit * 8 + half] = pk;
        }
    }
#pragma unroll
    for (int kh = 0; kh < 2; ++kh) {
      bf16x8 vf = *(const bf16x8*)&VtF[(kh * 64 + l) * 8];
#pragma unroll
      for (int g = 0; g < 2; ++g) {
        bf16x8 pf = *(const bf16x8*)&PsF[w][((kh * 2 + g) * 64 + l) * 8];
        oacc[g] = MFMA16(pf, vf, oacc[g]);
        lacc[g] = MFMA16(pf, ones, lacc[g]);
      }
    }
  }
#pragma unroll
  for (int g = 0; g < 2; ++g)
#pragma unroll
    for (int r = 0; r < 4; ++r) {
      int qq = qbase + g * 16 + (l >> 4) * 4 + r;
      if (qq < NT_)
        ab[((size_t)b * NT_ + qq) * 128 + hd * 16 + (l & 15)] = (bf16)(oacc[g][r] / lacc[g][r]);
    }
}

// ---------------- BN finalize (parallel, column-major partials) ----------------
__global__ __launch_bounds__(512) void stats_final(
    const float* __restrict__ ps, const float* __restrict__ pq,
    const float* __restrict__ sc, const float* __restrict__ bi, float* __restrict__ mi) {
  int tid = threadIdx.x;
  int c = tid >> 2, q4 = tid & 3;
  float s = 0.f, q = 0.f;
  for (int p = q4; p < 501; p += 4) { s += ps[c * 512 + p]; q += pq[c * 512 + p]; }
  s += __shfl_xor(s, 1); s += __shfl_xor(s, 2);
  q += __shfl_xor(q, 1); q += __shfl_xor(q, 2);
  if (q4 == 0) {
    float mean = s * (1.f / (float)ROWS);
    float var = q * (1.f / (float)ROWS) - mean * mean;
    float s2 = sc[c] * rsqrtf(var + 1e-5f);
    mi[c] = s2;
    mi[128 + c] = bi[c] - mean * s2;
  }
}

// ---------------- decoder ----------------
__global__ void ge_partial(const bf16* __restrict__ X, const float* __restrict__ mi,
                           float* __restrict__ part) {
  int b = blockIdx.x, ch = blockIdx.y, d = threadIdx.x;
  int n0 = ch * 126, n1 = n0 + 126; if (n1 > NT_) n1 = NT_;
  float sS = mi[d], sB = mi[128 + d];
  float s = 0.f;
  for (int n = n0; n < n1; ++n)
    s += __builtin_fmaf((float)X[((size_t)b * NT_ + n) * D_ + d], sS, sB);
  part[(b * 8 + ch) * D_ + d] = s;
}

__global__ void query_kernel(const float* __restrict__ part, const bf16* __restrict__ X,
                             const float* __restrict__ mi,
                             const float* __restrict__ Wf, const float* __restrict__ Ws,
                             float* __restrict__ qry) {
  __shared__ float sge[128], sh0[128];
  int b = blockIdx.x, d = threadIdx.x;
  float s = 0.f;
#pragma unroll
  for (int ch = 0; ch < 8; ++ch) s += part[(b * 8 + ch) * D_ + d];
  sge[d] = s * (1.f / (float)NT_);
  sh0[d] = __builtin_fmaf((float)X[(size_t)b * NT_ * D_ + d], mi[d], mi[128 + d]);
  __syncthreads();
  float q = 0.f;
  for (int k = 0; k < 128; ++k) q += sge[k] * Wf[k * D_ + d] + sh0[k] * Ws[k * D_ + d];
  qry[b * D_ + d] = q;
}

__global__ __launch_bounds__(256) void glimpse_kernel(
    const bf16* __restrict__ proj, const float* __restrict__ qry,
    const int* __restrict__ mask, float* __restrict__ glimpse) {
  int bid = blockIdx.x; int b = bid >> 3, hd = bid & 7;
  int tid = threadIdx.x;
  __shared__ float sq[16];
  __shared__ float sex[NT_];
  __shared__ float rmax[4];
  __shared__ float wacc[4][17];
  if (tid < 16) sq[tid] = qry[b * 128 + hd * 16 + tid];
  __syncthreads();
  const bf16* P = proj + (size_t)b * NT_ * 384;
  const int* Mk = mask + b * NT_;
  float lmax = -1e30f;
#pragma unroll
  for (int it = 0; it < 4; ++it) {
    int n = tid + it * 256;
    if (n < NT_) {
      float c = NEGV;
      if (!Mk[n]) {
        const bf16* kp = &P[(size_t)n * 384 + hd * 16];
        bf16x8 k0 = *(const bf16x8*)kp, k1 = *(const bf16x8*)(kp + 8);
        float d = 0.f;
#pragma unroll
        for (int i = 0; i < 8; ++i) d += sq[i] * (float)k0[i] + sq[8 + i] * (float)k1[i];
        c = d * 0.25f;
      }
      sex[n] = c;
      lmax = fmaxf(lmax, c);
    }
  }
#pragma unroll
  for (int o = 32; o > 0; o >>= 1) lmax = fmaxf(lmax, __shfl_xor(lmax, o));
  if ((tid & 63) == 0) rmax[tid >> 6] = lmax;
  __syncthreads();
  float mx = fmaxf(fmaxf(rmax[0], rmax[1]), fmaxf(rmax[2], rmax[3]));
  float acc[16];
#pragma unroll
  for (int i = 0; i < 16; ++i) acc[i] = 0.f;
  float lsum = 0.f;
#pragma unroll
  for (int it = 0; it < 4; ++it) {
    int n = tid + it * 256;
    if (n < NT_) {
      float e = __expf(sex[n] - mx);
      lsum += e;
      const bf16* vp = &P[(size_t)n * 384 + 128 + hd * 16];
      bf16x8 v0 = *(const bf16x8*)vp, v1 = *(const bf16x8*)(vp + 8);
#pragma unroll
      for (int i = 0; i < 8; ++i) { acc[i] += e * (float)v0[i]; acc[8 + i] += e * (float)v1[i]; }
    }
  }
#pragma unroll
  for (int o = 32; o > 0; o >>= 1) {
    lsum += __shfl_xor(lsum, o);
#pragma unroll
    for (int i = 0; i < 16; ++i) acc[i] += __shfl_xor(acc[i], o);
  }
  if ((tid & 63) == 0) {
    wacc[tid >> 6][16] = lsum;
#pragma unroll
    for (int i = 0; i < 16; ++i) wacc[tid >> 6][i] = acc[i];
  }
  __syncthreads();
  if (tid < 16) {
    float a = wacc[0][tid] + wacc[1][tid] + wacc[2][tid] + wacc[3][tid];
    float L = wacc[0][16] + wacc[1][16] + wacc[2][16] + wacc[3][16];
    glimpse[b * 128 + hd * 16 + tid] = a / L;
  }
}

__global__ void g2_kernel(const float* __restrict__ glimpse, const float* __restrict__ Wout,
                          float* __restrict__ g2) {
  __shared__ float sg[128];
  int b = blockIdx.x, d = threadIdx.x;
  sg[d] = glimpse[b * 128 + d];
  __syncthreads();
  float s = 0.f;
  for (int k = 0; k < 128; ++k) s += sg[k] * Wout[k * 128 + d];
  g2[b * 128 + d] = s;
}

__global__ __launch_bounds__(256) void logits_kernel(
    const bf16* __restrict__ proj, const float* __restrict__ g2,
    const int* __restrict__ mask, float* __restrict__ logits) {
  int b = blockIdx.y;
  int n = blockIdx.x * 256 + threadIdx.x;
  __shared__ float sg[128];
  if (threadIdx.x < 128) sg[threadIdx.x] = g2[b * 128 + threadIdx.x];
  __syncthreads();
  if (n >= NT_) return;
  const bf16* kp = &proj[((size_t)b * NT_ + n) * 384 + 256];
  float d = 0.f;
#pragma unroll
  for (int j = 0; j < 16; ++j) {
    bf16x8 v = *(const bf16x8*)&kp[j * 8];
#pragma unroll
    for (int i = 0; i < 8; ++i) d += sg[j * 8 + i] * (float)v[i];
  }
  d = 10.f * tanhf(d * 0.088388347648318447f);
  logits[b * NT_ + n] = mask[b * NT_ + n] ? NEGV : d;
}

__global__ __launch_bounds__(256) void lsm_kernel(const float* __restrict__ logits, float* __restrict__ out) {
  int b = blockIdx.x, tid = threadIdx.x;
  __shared__ float red[256];
  float mx = -1e30f;
  for (int n = tid; n < NT_; n += 256) mx = fmaxf(mx, logits[b * NT_ + n]);
  red[tid] = mx; __syncthreads();
  for (int s = 128; s > 0; s >>= 1) { if (tid < s) red[tid] = fmaxf(red[tid], red[tid + s]); __syncthreads(); }
  mx = red[0]; __syncthreads();
  float sm = 0.f;
  for (int n = tid; n < NT_; n += 256) sm += __expf(logits[b * NT_ + n] - mx);
  red[tid] = sm; __syncthreads();
  for (int s = 128; s > 0; s >>= 1) { if (tid < s) red[tid] += red[tid + s]; __syncthreads(); }
  float lse = mx + logf(red[0]);
  for (int n = tid; n < NT_; n += 256) out[(size_t)b * NT_ + n] = logits[b * NT_ + n] - lse;
}

// ---------------- launcher ----------------
extern "C" void kernel_launch(void* const* d_in, const int* in_sizes, int n_in,
                              void* d_out, int out_size, void* d_ws, size_t ws_size,
                              hipStream_t stream) {
  const float* depot        = (const float*)d_in[0];
  const float* loc          = (const float*)d_in[1];
  const float* demand       = (const float*)d_in[2];
  const int*   mask         = (const int*)d_in[3];
  const float* W_init_node  = (const float*)d_in[4];
  const float* b_init_node  = (const float*)d_in[5];
  const float* W_init_depot = (const float*)d_in[6];
  const float* b_init_depot = (const float*)d_in[7];
  const float* enc_Wqkv     = (const float*)d_in[8];
  const float* enc_Wo       = (const float*)d_in[9];
  const float* enc_W1       = (const float*)d_in[10];
  const float* enc_b1       = (const float*)d_in[11];
  const float* enc_W2       = (const float*)d_in[12];
  const float* enc_b2       = (const float*)d_in[13];
  const float* bn1_s        = (const float*)d_in[14];
  const float* bn1_b        = (const float*)d_in[15];
  const float* bn2_s        = (const float*)d_in[16];
  const float* bn2_b        = (const float*)d_in[17];
  const float* W_proj       = (const float*)d_in[18];
  const float* W_fixed      = (const float*)d_in[19];
  const float* W_step       = (const float*)d_in[20];
  const float* W_out        = (const float*)d_in[21];
  float* out = (float*)d_out;

  char* base = (char*)d_ws;
  bf16*  hb0   = (bf16*)(base);                        // 8,208,384
  bf16*  ab    = (bf16*)(base + 8208384);              // 8,208,384
  bf16*  Qh    = (bf16*)(base + 16416768);             // 8,388,608 [bh][NTP][16]
  bf16*  Kh    = (bf16*)(base + 24805376);             // 8,388,608
  bf16*  Vh    = (bf16*)(base + 33193984);             // 8,388,608 [bh*16+c16][NTP]
  bf16*  xb1   = Qh;                                   // alias (post-mattn lifetime)
  bf16*  xb2   = (bf16*)(base + 41582592);             // 8,208,384
  bf16*  projb = (bf16*)(base + 49790976);             // 24,625,152
  bf16*  wb    = (bf16*)(base + 74416128);             // 884,736
  float* ps    = (float*)(base + 75300864);            // 262,144 [128 col][512]
  float* pq    = (float*)(base + 75563008);            // 262,144
  float* mi1   = (float*)(base + 75825152);            // 1,024
  float* mi2   = (float*)(base + 75826176);            // 1,024
  float* qry   = (float*)(base + 75827200);            // 16,384
  float* glim  = (float*)(base + 75843584);            // 16,384
  float* g2    = (float*)(base + 75859968);            // 16,384
  float* gep   = ps;                                   // decoder reuse
  float* logit = pq;                                   // decoder reuse

  bf16* wt_qkv  = wb;
  bf16* wt_wo   = wb + SZ_QKV;
  bf16* wt_w1   = wb + SZ_QKV + SZ_WO;
  bf16* wt_w2   = wb + SZ_QKV + SZ_WO + SZ_W1;
  bf16* wt_proj = wb + SZ_QKV + SZ_WO + SZ_W1 + SZ_W2;

  prep_w<<<1728, 256, 0, stream>>>(enc_Wqkv, enc_Wo, enc_W1, enc_W2, W_proj, wb);
  init_kernel<<<(ROWS * D_ + 255) / 256, 256, 0, stream>>>(
      depot, loc, demand, W_init_node, b_init_node, W_init_depot, b_init_depot, hb0);

  for (int l = 0; l < 2; ++l) {
    const bf16* hin = (l == 0) ? hb0 : xb2;
    if (l == 0)
      mgemm_qkv<false><<<dim3(3, 501), 256, 0, stream>>>(hin, wt_qkv, nullptr, Qh, Kh, Vh);
    else
      mgemm_qkv<true><<<dim3(3, 501), 256, 0, stream>>>(hin, wt_qkv + (size_t)384 * 128, mi2, Qh, Kh, Vh);
    mattn<<<dim3(256, 8), 256, 0, stream>>>(Qh, Kh, Vh, ab);
    if (l == 0)
      mgemm<128, 128, false, false, true, true, false, false><<<dim3(1, 501), 256, 0, stream>>>(
          ab, wt_wo, nullptr, hin, xb1, ps, pq, nullptr, nullptr);
    else
      mgemm<128, 128, false, false, true, true, false, true><<<dim3(1, 501), 256, 0, stream>>>(
          ab, wt_wo + (size_t)128 * 128, nullptr, hin, xb1, ps, pq, nullptr, mi2);
    stats_final<<<1, 512, 0, stream>>>(ps, pq, bn1_s + l * D_, bn1_b + l * D_, mi1);
    fffused<<<501, 256, 0, stream>>>(
        xb1, mi1, wt_w1 + (size_t)l * 512 * 128, enc_b1 + (size_t)l * FF_,
        wt_w2 + (size_t)l * 128 * 512, enc_b2 + (size_t)l * D_, xb2, ps, pq);
    stats_final<<<1, 512, 0, stream>>>(ps, pq, bn2_s + l * D_, bn2_b + l * D_, mi2);
  }

  // decoder
  mgemm<384, 128, false, false, false, false, true, false><<<dim3(3, 501), 256, 0, stream>>>(
      xb2, wt_proj, nullptr, nullptr, projb, nullptr, nullptr, mi2, nullptr);
  ge_partial<<<dim3(32, 8), 128, 0, stream>>>(xb2, mi2, gep);
  query_kernel<<<32, 128, 0, stream>>>(gep, xb2, mi2, W_fixed, W_step, qry);
  glimpse_kernel<<<256, 256, 0, stream>>>(projb, qry, mask, glim);
  g2_kernel<<<32, 128, 0, stream>>>(glim, W_out, g2);
  logits_kernel<<<dim3(4, 32), 256, 0, stream>>>(projb, g2, mask, logit);
  lsm_kernel<<<32, 256, 0, stream>>>(logit, out);
}

// Round 12
// 359.792 us; speedup vs baseline: 1.1141x; 1.0585x over previous
//
#include <hip/hip_runtime.h>

#define B_   32
#define NT_  1002
#define D_   128
#define H_   8
#define FF_  512
#define ROWS (B_ * NT_)          // 32064 = 501*64
#define NEGV (-1e9f)
#define NTP  1024                // padded rows per (b,head)

typedef __bf16 bf16;
typedef __bf16 bf16x8 __attribute__((ext_vector_type(8)));
typedef __bf16 bf16x4 __attribute__((ext_vector_type(4)));
typedef float  f32x4  __attribute__((ext_vector_type(4)));
typedef float  f32x16 __attribute__((ext_vector_type(16)));

#if __has_builtin(__builtin_amdgcn_exp2f)
#define EXP2(x) __builtin_amdgcn_exp2f(x)
#else
#define EXP2(x) exp2f(x)
#endif

#define MFMA16(a, b, c) __builtin_amdgcn_mfma_f32_16x16x32_bf16(a, b, c, 0, 0, 0)
#define MFMA32(a, b, c) __builtin_amdgcn_mfma_f32_32x32x16_bf16(a, b, c, 0, 0, 0)

// unit-linear LDS tile addressing: 16B unit for (row, 8-elem k-seg), 32-k tiles
__device__ __forceinline__ int UNIT(int row, int seg) {
  return (row >> 4) * 64 + seg * 16 + (row & 15);
}
// 128-k tiles (16 segs)
__device__ __forceinline__ int UNIT128(int row, int seg) {
  return (row >> 4) * 256 + seg * 16 + (row & 15);
}

// ---------------- weight prep: transpose + convert to bf16 [n][k] ----------------
#define SZ_QKV (2*384*128)
#define SZ_WO  (2*128*128)
#define SZ_W1  (2*512*128)
#define SZ_W2  (2*128*512)
#define SZ_PROJ (384*128)

__global__ __launch_bounds__(256) void prep_w(
    const float* __restrict__ qkv, const float* __restrict__ wo, const float* __restrict__ w1,
    const float* __restrict__ w2, const float* __restrict__ proj, bf16* __restrict__ out) {
  int i = blockIdx.x * 256 + threadIdx.x;
  int j = i;
  float v;
  if (j < SZ_QKV) {
    int l = j / 49152, r = j % 49152; int n = r >> 7, k = r & 127;
    v = qkv[((size_t)l * 128 + k) * 384 + n];
  } else {
    j -= SZ_QKV;
    if (j < SZ_WO) {
      int l = j >> 14, r = j & 16383; int n = r >> 7, k = r & 127;
      v = wo[((size_t)l * 128 + k) * 128 + n];
    } else {
      j -= SZ_WO;
      if (j < SZ_W1) {
        int l = j >> 16, r = j & 65535; int n = r >> 7, k = r & 127;
        v = w1[((size_t)l * 128 + k) * 512 + n];
      } else {
        j -= SZ_W1;
        if (j < SZ_W2) {
          int l = j >> 16, r = j & 65535; int n = r >> 9, k = r & 511;
          v = w2[((size_t)l * 512 + k) * 128 + n];
        } else {
          j -= SZ_W2;
          int n = j >> 7, k = j & 127;
          v = proj[(size_t)k * 384 + n];
        }
      }
    }
  }
  out[i] = (bf16)v;
}

// ---------------- init embeddings (bf16) ----------------
__global__ __launch_bounds__(256) void init_kernel(
    const float* __restrict__ depot, const float* __restrict__ loc, const float* __restrict__ demand,
    const float* __restrict__ Wn, const float* __restrict__ bn_, const float* __restrict__ Wd,
    const float* __restrict__ bd, bf16* __restrict__ hb) {
  int idx = blockIdx.x * 256 + threadIdx.x;
  if (idx >= ROWS * D_) return;
  int c = idx & 127;
  int row = idx >> 7;
  int b = row / NT_;
  int n = row - b * NT_;
  float v;
  if (n < 2) {
    const float* dp = depot + (b * 2 + n) * 2;
    v = dp[0] * Wd[c] + dp[1] * Wd[D_ + c] + bd[c];
  } else {
    int i = n - 2;
    const float* lp = loc + ((size_t)b * 1000 + i) * 2;
    v = lp[0] * Wn[c] + lp[1] * Wn[D_ + c] + demand[b * 1000 + i] * Wn[2 * D_ + c] + bn_[c];
  }
  hb[idx] = (bf16)v;
}

// ---------------- MFMA GEMM (R8): tile 64(M) x 128(N), LDS-staged A and B ----------------
// A [ROWS][K_] bf16, Wt [N][K] bf16; STATS partials column-major ps[(bn+c)*512 + by]
template<int N_, int K_, bool BIAS, bool RELU, bool RES, bool STATS, bool BNA, bool BNR>
__global__ __launch_bounds__(256) void mgemm(
    const bf16* __restrict__ A, const bf16* __restrict__ Wt,
    const float* __restrict__ bias, const bf16* __restrict__ R, bf16* __restrict__ Cout,
    float* __restrict__ ps, float* __restrict__ pq,
    const float* __restrict__ miA, const float* __restrict__ miR) {
  __shared__ bf16 AsF[2048];
  __shared__ bf16 BsF[4096];
  __shared__ float sredS[4][64];
  __shared__ float sredQ[4][64];
  int tid = threadIdx.x;
  int w = tid >> 6, l = tid & 63;
  int bm = blockIdx.y * 64, bn = blockIdx.x * 128;
  int wr = (w >> 1) * 32, wc = (w & 1) * 64;
  f32x4 acc[2][4] = {};
  int srow = tid >> 2, sseg = tid & 3;
  int uA = UNIT(srow, sseg) * 8;
  int uB0 = UNIT(srow, sseg) * 8, uB1 = UNIT(srow + 64, sseg) * 8;
  for (int k0 = 0; k0 < K_; k0 += 32) {
    __syncthreads();
    {
      bf16x8 x = *(const bf16x8*)&A[(size_t)(bm + srow) * K_ + k0 + sseg * 8];
      if (BNA) {
        int kc = k0 + sseg * 8;
        f32x4 s0 = *(const f32x4*)&miA[kc],       s1 = *(const f32x4*)&miA[kc + 4];
        f32x4 c0 = *(const f32x4*)&miA[128 + kc], c1 = *(const f32x4*)&miA[128 + kc + 4];
        bf16x8 y;
#pragma unroll
        for (int i = 0; i < 4; ++i) y[i] = (bf16)__builtin_fmaf((float)x[i], s0[i], c0[i]);
#pragma unroll
        for (int i = 0; i < 4; ++i) y[4 + i] = (bf16)__builtin_fmaf((float)x[4 + i], s1[i], c1[i]);
        *(bf16x8*)&AsF[uA] = y;
      } else {
        *(bf16x8*)&AsF[uA] = x;
      }
    }
    *(bf16x8*)&BsF[uB0] = *(const bf16x8*)&Wt[(size_t)(bn + srow) * K_ + k0 + sseg * 8];
    *(bf16x8*)&BsF[uB1] = *(const bf16x8*)&Wt[(size_t)(bn + srow + 64) * K_ + k0 + sseg * 8];
    __syncthreads();
    bf16x8 af[2], bfr[4];
#pragma unroll
    for (int mi = 0; mi < 2; ++mi)
      af[mi] = *(const bf16x8*)&AsF[(((wr >> 4) + mi) * 64 + (l >> 4) * 16 + (l & 15)) * 8];
#pragma unroll
    for (int ni = 0; ni < 4; ++ni)
      bfr[ni] = *(const bf16x8*)&BsF[(((wc >> 4) + ni) * 64 + (l >> 4) * 16 + (l & 15)) * 8];
#pragma unroll
    for (int mi = 0; mi < 2; ++mi)
#pragma unroll
      for (int ni = 0; ni < 4; ++ni)
        acc[mi][ni] = MFMA16(af[mi], bfr[ni], acc[mi][ni]);
  }
  float scol[4] = {}, qcol[4] = {};
#pragma unroll
  for (int mi = 0; mi < 2; ++mi)
#pragma unroll
    for (int ni = 0; ni < 4; ++ni) {
      int col = bn + wc + ni * 16 + (l & 15);
      float rs = 1.f, rb = 0.f;
      if (RES && BNR) { rs = miR[col]; rb = miR[128 + col]; }
#pragma unroll
      for (int r = 0; r < 4; ++r) {
        int row = bm + wr + mi * 16 + (l >> 4) * 4 + r;
        float v = acc[mi][ni][r];
        if (BIAS) v += bias[col];
        if (RELU) v = fmaxf(v, 0.f);
        if (RES) {
          float x = (float)R[(size_t)row * N_ + col];
          v += BNR ? __builtin_fmaf(x, rs, rb) : x;
        }
        if (STATS) { scol[ni] += v; qcol[ni] += v * v; }
        Cout[(size_t)row * N_ + col] = (bf16)v;
      }
    }
  if (STATS) {
#pragma unroll
    for (int ni = 0; ni < 4; ++ni) {
      scol[ni] += __shfl_xor(scol[ni], 16); scol[ni] += __shfl_xor(scol[ni], 32);
      qcol[ni] += __shfl_xor(qcol[ni], 16); qcol[ni] += __shfl_xor(qcol[ni], 32);
    }
    __syncthreads();
    if (l < 16) {
#pragma unroll
      for (int ni = 0; ni < 4; ++ni) {
        sredS[w][ni * 16 + l] = scol[ni];
        sredQ[w][ni * 16 + l] = qcol[ni];
      }
    }
    __syncthreads();
    if (tid < 128) {
      int c = tid, cw = c >> 6, cc = c & 63;
      ps[(size_t)(bn + c) * 512 + blockIdx.y] = sredS[cw][cc] + sredS[cw + 2][cc];
      pq[(size_t)(bn + c) * 512 + blockIdx.y] = sredQ[cw][cc] + sredQ[cw + 2][cc];
    }
  }
}

// ---------------- QKV GEMM (R8): x=0 -> Q (pre-scaled by SC), x=1 -> K, x=2 -> V(transposed) ----------------
template<bool BNA>
__global__ __launch_bounds__(256) void mgemm_qkv(
    const bf16* __restrict__ A, const bf16* __restrict__ Wt, const float* __restrict__ miA,
    bf16* __restrict__ Qh, bf16* __restrict__ Kh, bf16* __restrict__ Vh) {
  __shared__ bf16 smem[128 * 68];     // As(2048) + Bs(4096) | Vt2(128x68)
  bf16* AsF = smem;
  bf16* BsF = smem + 2048;
  bf16* Vt2 = smem;
  int tid = threadIdx.x;
  int w = tid >> 6, l = tid & 63;
  int bm = blockIdx.y * 64, bn = blockIdx.x * 128;
  int wr = (w >> 1) * 32, wc = (w & 1) * 64;
  f32x4 acc[2][4] = {};
  int srow = tid >> 2, sseg = tid & 3;
  int uA = UNIT(srow, sseg) * 8;
  int uB0 = UNIT(srow, sseg) * 8, uB1 = UNIT(srow + 64, sseg) * 8;
  for (int k0 = 0; k0 < 128; k0 += 32) {
    __syncthreads();
    {
      bf16x8 x = *(const bf16x8*)&A[(size_t)(bm + srow) * 128 + k0 + sseg * 8];
      if (BNA) {
        int kc = k0 + sseg * 8;
        f32x4 s0 = *(const f32x4*)&miA[kc],       s1 = *(const f32x4*)&miA[kc + 4];
        f32x4 c0 = *(const f32x4*)&miA[128 + kc], c1 = *(const f32x4*)&miA[128 + kc + 4];
        bf16x8 y;
#pragma unroll
        for (int i = 0; i < 4; ++i) y[i] = (bf16)__builtin_fmaf((float)x[i], s0[i], c0[i]);
#pragma unroll
        for (int i = 0; i < 4; ++i) y[4 + i] = (bf16)__builtin_fmaf((float)x[4 + i], s1[i], c1[i]);
        *(bf16x8*)&AsF[uA] = y;
      } else {
        *(bf16x8*)&AsF[uA] = x;
      }
    }
    *(bf16x8*)&BsF[uB0] = *(const bf16x8*)&Wt[(size_t)(bn + srow) * 128 + k0 + sseg * 8];
    *(bf16x8*)&BsF[uB1] = *(const bf16x8*)&Wt[(size_t)(bn + srow + 64) * 128 + k0 + sseg * 8];
    __syncthreads();
    bf16x8 af[2], bfr[4];
#pragma unroll
    for (int mi = 0; mi < 2; ++mi)
      af[mi] = *(const bf16x8*)&AsF[(((wr >> 4) + mi) * 64 + (l >> 4) * 16 + (l & 15)) * 8];
#pragma unroll
    for (int ni = 0; ni < 4; ++ni)
      bfr[ni] = *(const bf16x8*)&BsF[(((wc >> 4) + ni) * 64 + (l >> 4) * 16 + (l & 15)) * 8];
#pragma unroll
    for (int mi = 0; mi < 2; ++mi)
#pragma unroll
      for (int ni = 0; ni < 4; ++ni)
        acc[mi][ni] = MFMA16(af[mi], bfr[ni], acc[mi][ni]);
  }
  if (blockIdx.x < 2) {
    bf16* dst = (blockIdx.x == 0) ? Qh : Kh;
    // fold softmax scale (1/sqrt(dk) * log2(e)) into Q so mattn's exp arg is raw MFMA output
    float qs = (blockIdx.x == 0) ? 0.36067376022224085f : 1.0f;
#pragma unroll
    for (int ni = 0; ni < 4; ++ni) {
      int cl = wc + ni * 16 + (l & 15);
      int hd = cl >> 4, c16 = cl & 15;
#pragma unroll
      for (int mi = 0; mi < 2; ++mi)
#pragma unroll
        for (int r = 0; r < 4; ++r) {
          int row = bm + wr + mi * 16 + (l >> 4) * 4 + r;
          int b = row / NT_;
          int n = row - b * NT_;
          dst[(((size_t)b * 8 + hd) * NTP + n) * 16 + c16] = (bf16)(acc[mi][ni][r] * qs);
        }
    }
  } else {
    __syncthreads();
#pragma unroll
    for (int mi = 0; mi < 2; ++mi)
#pragma unroll
      for (int ni = 0; ni < 4; ++ni) {
        int cl = wc + ni * 16 + (l & 15);
        int r0 = wr + mi * 16 + (l >> 4) * 4;
        bf16x4 pk;
#pragma unroll
        for (int r = 0; r < 4; ++r) pk[r] = (bf16)acc[mi][ni][r];
        *(bf16x4*)&Vt2[cl * 68 + r0] = pk;
      }
    __syncthreads();
    int colg = tid >> 4, nl = tid & 15;
#pragma unroll
    for (int ci = 0; ci < 8; ++ci) {
      int lc = colg + ci * 16;
      int hd = lc >> 4, c16 = lc & 15;
#pragma unroll
      for (int ri = 0; ri < 4; ++ri) {
        int lrow = nl + ri * 16;
        int row = bm + lrow;
        int b = row / NT_;
        int n = row - b * NT_;
        Vh[(((size_t)b * 8 + hd) * 16 + c16) * NTP + n] = Vt2[lc * 68 + lrow];
      }
    }
  }
}

// ---------------- fused FF (R8): y = relu(bn1(x)@W1+b1)@W2 + b2 + bn1(x), + stats ----------------
__global__ __launch_bounds__(256) void fffused(
    const bf16* __restrict__ X, const float* __restrict__ mi,
    const bf16* __restrict__ W1t, const float* __restrict__ bias1,
    const bf16* __restrict__ W2t, const float* __restrict__ bias2,
    bf16* __restrict__ Y, float* __restrict__ ps, float* __restrict__ pq) {
  __shared__ bf16 A1[8192];   // 64 x 128, unit-linear
  __shared__ bf16 A2[8192];   // 64 x 128 (ff chunk), unit-linear
  __shared__ bf16 BF[4096];   // 128 x 32 weight staging
  __shared__ float sredS[4][64];
  __shared__ float sredQ[4][64];
  int tid = threadIdx.x;
  int w = tid >> 6, l = tid & 63;
  int bm = blockIdx.x * 64;
#pragma unroll
  for (int it = 0; it < 4; ++it) {
    int idx = it * 256 + tid;
    int row = idx >> 4, seg = idx & 15;
    bf16x8 x = *(const bf16x8*)&X[(size_t)(bm + row) * 128 + seg * 8];
    f32x4 s0 = *(const f32x4*)&mi[seg * 8],       s1 = *(const f32x4*)&mi[seg * 8 + 4];
    f32x4 c0 = *(const f32x4*)&mi[128 + seg * 8], c1 = *(const f32x4*)&mi[128 + seg * 8 + 4];
    bf16x8 y;
#pragma unroll
    for (int i = 0; i < 4; ++i) y[i] = (bf16)__builtin_fmaf((float)x[i], s0[i], c0[i]);
#pragma unroll
    for (int i = 0; i < 4; ++i) y[4 + i] = (bf16)__builtin_fmaf((float)x[4 + i], s1[i], c1[i]);
    *(bf16x8*)&A1[UNIT128(row, seg) * 8] = y;
  }
  int srow = tid >> 2, sseg = tid & 3;
  int uB0 = UNIT(srow, sseg) * 8, uB1 = UNIT(srow + 64, sseg) * 8;
  int wr = (w >> 1) * 32, wc = (w & 1) * 64;
  f32x4 acc2[2][4] = {};

  for (int nc = 0; nc < 4; ++nc) {
    f32x4 acc1[2][4] = {};
    for (int k0 = 0; k0 < 128; k0 += 32) {
      __syncthreads();
      *(bf16x8*)&BF[uB0] = *(const bf16x8*)&W1t[(size_t)(nc * 128 + srow) * 128 + k0 + sseg * 8];
      *(bf16x8*)&BF[uB1] = *(const bf16x8*)&W1t[(size_t)(nc * 128 + srow + 64) * 128 + k0 + sseg * 8];
      __syncthreads();
      bf16x8 af[2], hf[4];
#pragma unroll
      for (int m2 = 0; m2 < 2; ++m2)
        af[m2] = *(const bf16x8*)&BF[((w * 2 + m2) * 64 + (l >> 4) * 16 + (l & 15)) * 8];
#pragma unroll
      for (int ni = 0; ni < 4; ++ni)
        hf[ni] = *(const bf16x8*)&A1[(ni * 256 + ((k0 >> 3) + (l >> 4)) * 16 + (l & 15)) * 8];
#pragma unroll
      for (int m2 = 0; m2 < 2; ++m2)
#pragma unroll
        for (int ni = 0; ni < 4; ++ni)
          acc1[m2][ni] = MFMA16(af[m2], hf[ni], acc1[m2][ni]);
    }
#pragma unroll
    for (int m2 = 0; m2 < 2; ++m2) {
      int ffk0 = w * 32 + m2 * 16 + (l >> 4) * 4;
      int seg = ffk0 >> 3, half = ffk0 & 7;
#pragma unroll
      for (int ni = 0; ni < 4; ++ni) {
        bf16x4 pk;
#pragma unroll
        for (int r = 0; r < 4; ++r) {
          float v = acc1[m2][ni][r] + bias1[nc * 128 + ffk0 + r];
          pk[r] = (bf16)fmaxf(v, 0.f);
        }
        *(bf16x4*)&A2[(ni * 256 + seg * 16 + (l & 15)) * 8 + half] = pk;
      }
    }
    __syncthreads();
    for (int k0 = 0; k0 < 128; k0 += 32) {
      if (k0) __syncthreads();
      *(bf16x8*)&BF[uB0] = *(const bf16x8*)&W2t[(size_t)srow * 512 + nc * 128 + k0 + sseg * 8];
      *(bf16x8*)&BF[uB1] = *(const bf16x8*)&W2t[(size_t)(srow + 64) * 512 + nc * 128 + k0 + sseg * 8];
      __syncthreads();
      bf16x8 a2f[2], b2f[4];
#pragma unroll
      for (int m2 = 0; m2 < 2; ++m2)
        a2f[m2] = *(const bf16x8*)&A2[(((wr >> 4) + m2) * 256 + ((k0 >> 3) + (l >> 4)) * 16 + (l & 15)) * 8];
#pragma unroll
      for (int ni = 0; ni < 4; ++ni)
        b2f[ni] = *(const bf16x8*)&BF[(((wc >> 4) + ni) * 64 + (l >> 4) * 16 + (l & 15)) * 8];
#pragma unroll
      for (int m2 = 0; m2 < 2; ++m2)
#pragma unroll
        for (int ni = 0; ni < 4; ++ni)
          acc2[m2][ni] = MFMA16(a2f[m2], b2f[ni], acc2[m2][ni]);
    }
  }
  float scol[4] = {}, qcol[4] = {};
#pragma unroll
  for (int m2 = 0; m2 < 2; ++m2)
#pragma unroll
    for (int ni = 0; ni < 4; ++ni) {
      int col = wc + ni * 16 + (l & 15);
      float bb = bias2[col];
#pragma unroll
      for (int r = 0; r < 4; ++r) {
        int row = wr + m2 * 16 + (l >> 4) * 4 + r;
        float res = (float)A1[UNIT128(row, col >> 3) * 8 + (col & 7)];
        float v = acc2[m2][ni][r] + bb + res;
        scol[ni] += v; qcol[ni] += v * v;
        Y[(size_t)(bm + row) * 128 + col] = (bf16)v;
      }
    }
#pragma unroll
  for (int ni = 0; ni < 4; ++ni) {
    scol[ni] += __shfl_xor(scol[ni], 16); scol[ni] += __shfl_xor(scol[ni], 32);
    qcol[ni] += __shfl_xor(qcol[ni], 16); qcol[ni] += __shfl_xor(qcol[ni], 32);
  }
  __syncthreads();
  if (l < 16) {
#pragma unroll
    for (int ni = 0; ni < 4; ++ni) {
      sredS[w][ni * 16 + l] = scol[ni];
      sredQ[w][ni * 16 + l] = qcol[ni];
    }
  }
  __syncthreads();
  if (tid < 128) {
    int c = tid, cw = c >> 6, cc = c & 63;
    ps[(size_t)c * 512 + blockIdx.x] = sredS[cw][cc] + sredS[cw + 2][cc];
    pq[(size_t)c * 512 + blockIdx.x] = sredQ[cw][cc] + sredQ[cw + 2][cc];
  }
}

// ---------------- MFMA flash attention V3.1: Q pre-scaled -> exp2 direct; setprio on MFMA ----------------
__global__ __launch_bounds__(256) void mattn(
    const bf16* __restrict__ Qh, const bf16* __restrict__ Kh,
    const bf16* __restrict__ Vh, bf16* __restrict__ ab) {
  __shared__ bf16 KsF[1024];
  __shared__ bf16 VtF[1024];
  __shared__ bf16 PsF[4][2048];
  int tid = threadIdx.x;
  int w = tid >> 6, l = tid & 63;
  int bh = blockIdx.x;
  int b = bh >> 3, hd = bh & 7;
  const bf16* Qp = Qh + (size_t)bh * NTP * 16;
  const bf16* Kp = Kh + (size_t)bh * NTP * 16;
  const bf16* Vp = Vh + (size_t)bh * 16 * NTP;
  int qbase = blockIdx.y * 128 + w * 32;
  int qrow = qbase + (l & 31); if (qrow >= NT_) qrow = NT_ - 1;
  bf16x8 qf = *(const bf16x8*)&Qp[qrow * 16 + (l >> 5) * 8];

  f32x4 oacc[2] = {};
  f32x4 lacc[2] = {};
  bf16x8 ones;
#pragma unroll
  for (int i = 0; i < 8; ++i) ones[i] = (bf16)1.0f;
  const f32x16 zz = {0,0,0,0,0,0,0,0,0,0,0,0,0,0,0,0};

  for (int t = 0; t < 16; ++t) {
    int kb = t * 64;
    __syncthreads();
    if (tid < 128) {
      int key = (tid >> 6) * 32 + (tid & 31);
      int h2 = (tid >> 5) & 1;
      int krow = kb + key; if (krow >= NT_) krow = NT_ - 1;
      *(bf16x8*)&KsF[tid * 8] = *(const bf16x8*)&Kp[krow * 16 + h2 * 8];
    } else {
      int u = tid - 128;
      int seg = u >> 4, dim = u & 15;
      *(bf16x8*)&VtF[u * 8] = *(const bf16x8*)&Vp[dim * NTP + kb + seg * 8];
    }
    __syncthreads();

    f32x16 sv[2];
    __builtin_amdgcn_s_setprio(1);
#pragma unroll
    for (int c = 0; c < 2; ++c) {
      bf16x8 kf = *(const bf16x8*)&KsF[(c * 64 + l) * 8];
      sv[c] = MFMA32(kf, qf, zz);
    }
    __builtin_amdgcn_s_setprio(0);
    if (kb + 64 > NT_) {
#pragma unroll
      for (int c = 0; c < 2; ++c)
#pragma unroll
        for (int r = 0; r < 16; ++r) {
          int key = kb + c * 32 + (r & 3) + 8 * (r >> 2) + 4 * (l >> 5);
          if (key >= NT_) sv[c][r] = -1e30f;
        }
    }
    // Q carries the 1/sqrt(dk)*log2(e) scale; exp arg is the raw score
#pragma unroll
    for (int c = 0; c < 2; ++c)
#pragma unroll
      for (int r = 0; r < 16; ++r)
        sv[c][r] = EXP2(sv[c][r]);
    {
      int q = l & 31;
      int qh4 = q >> 4, ql = q & 15, half = (l >> 5) * 4;
#pragma unroll
      for (int c = 0; c < 2; ++c)
#pragma unroll
        for (int g2 = 0; g2 < 4; ++g2) {
          bf16x4 pk;
#pragma unroll
          for (int i = 0; i < 4; ++i) pk[i] = (bf16)sv[c][g2 * 4 + i];
          int unit = (c * 2 + qh4) * 64 + g2 * 16 + ql;
          *(bf16x4*)&PsF[w][unit * 8 + half] = pk;
        }
    }
    __builtin_amdgcn_s_setprio(1);
#pragma unroll
    for (int kh = 0; kh < 2; ++kh) {
      bf16x8 vf = *(const bf16x8*)&VtF[(kh * 64 + l) * 8];
#pragma unroll
      for (int g = 0; g < 2; ++g) {
        bf16x8 pf = *(const bf16x8*)&PsF[w][((kh * 2 + g) * 64 + l) * 8];
        oacc[g] = MFMA16(pf, vf, oacc[g]);
        lacc[g] = MFMA16(pf, ones, lacc[g]);
      }
    }
    __builtin_amdgcn_s_setprio(0);
  }
#pragma unroll
  for (int g = 0; g < 2; ++g)
#pragma unroll
    for (int r = 0; r < 4; ++r) {
      int qq = qbase + g * 16 + (l >> 4) * 4 + r;
      if (qq < NT_)
        ab[((size_t)b * NT_ + qq) * 128 + hd * 16 + (l & 15)] = (bf16)(oacc[g][r] / lacc[g][r]);
    }
}

// ---------------- BN finalize (parallel, column-major partials) ----------------
__global__ __launch_bounds__(512) void stats_final(
    const float* __restrict__ ps, const float* __restrict__ pq,
    const float* __restrict__ sc, const float* __restrict__ bi, float* __restrict__ mi) {
  int tid = threadIdx.x;
  int c = tid >> 2, q4 = tid & 3;
  float s = 0.f, q = 0.f;
  for (int p = q4; p < 501; p += 4) { s += ps[c * 512 + p]; q += pq[c * 512 + p]; }
  s += __shfl_xor(s, 1); s += __shfl_xor(s, 2);
  q += __shfl_xor(q, 1); q += __shfl_xor(q, 2);
  if (q4 == 0) {
    float mean = s * (1.f / (float)ROWS);
    float var = q * (1.f / (float)ROWS) - mean * mean;
    float s2 = sc[c] * rsqrtf(var + 1e-5f);
    mi[c] = s2;
    mi[128 + c] = bi[c] - mean * s2;
  }
}

// ---------------- decoder ----------------
__global__ void ge_partial(const bf16* __restrict__ X, const float* __restrict__ mi,
                           float* __restrict__ part) {
  int b = blockIdx.x, ch = blockIdx.y, d = threadIdx.x;
  int n0 = ch * 126, n1 = n0 + 126; if (n1 > NT_) n1 = NT_;
  float sS = mi[d], sB = mi[128 + d];
  float s = 0.f;
  for (int n = n0; n < n1; ++n)
    s += __builtin_fmaf((float)X[((size_t)b * NT_ + n) * D_ + d], sS, sB);
  part[(b * 8 + ch) * D_ + d] = s;
}

__global__ void query_kernel(const float* __restrict__ part, const bf16* __restrict__ X,
                             const float* __restrict__ mi,
                             const float* __restrict__ Wf, const float* __restrict__ Ws,
                             float* __restrict__ qry) {
  __shared__ float sge[128], sh0[128];
  int b = blockIdx.x, d = threadIdx.x;
  float s = 0.f;
#pragma unroll
  for (int ch = 0; ch < 8; ++ch) s += part[(b * 8 + ch) * D_ + d];
  sge[d] = s * (1.f / (float)NT_);
  sh0[d] = __builtin_fmaf((float)X[(size_t)b * NT_ * D_ + d], mi[d], mi[128 + d]);
  __syncthreads();
  float q = 0.f;
  for (int k = 0; k < 128; ++k) q += sge[k] * Wf[k * D_ + d] + sh0[k] * Ws[k * D_ + d];
  qry[b * D_ + d] = q;
}

__global__ __launch_bounds__(256) void glimpse_kernel(
    const bf16* __restrict__ proj, const float* __restrict__ qry,
    const int* __restrict__ mask, float* __restrict__ glimpse) {
  int bid = blockIdx.x; int b = bid >> 3, hd = bid & 7;
  int tid = threadIdx.x;
  __shared__ float sq[16];
  __shared__ float sex[NT_];
  __shared__ float rmax[4];
  __shared__ float wacc[4][17];
  if (tid < 16) sq[tid] = qry[b * 128 + hd * 16 + tid];
  __syncthreads();
  const bf16* P = proj + (size_t)b * NT_ * 384;
  const int* Mk = mask + b * NT_;
  float lmax = -1e30f;
#pragma unroll
  for (int it = 0; it < 4; ++it) {
    int n = tid + it * 256;
    if (n < NT_) {
      float c = NEGV;
      if (!Mk[n]) {
        const bf16* kp = &P[(size_t)n * 384 + hd * 16];
        bf16x8 k0 = *(const bf16x8*)kp, k1 = *(const bf16x8*)(kp + 8);
        float d = 0.f;
#pragma unroll
        for (int i = 0; i < 8; ++i) d += sq[i] * (float)k0[i] + sq[8 + i] * (float)k1[i];
        c = d * 0.25f;
      }
      sex[n] = c;
      lmax = fmaxf(lmax, c);
    }
  }
#pragma unroll
  for (int o = 32; o > 0; o >>= 1) lmax = fmaxf(lmax, __shfl_xor(lmax, o));
  if ((tid & 63) == 0) rmax[tid >> 6] = lmax;
  __syncthreads();
  float mx = fmaxf(fmaxf(rmax[0], rmax[1]), fmaxf(rmax[2], rmax[3]));
  float acc[16];
#pragma unroll
  for (int i = 0; i < 16; ++i) acc[i] = 0.f;
  float lsum = 0.f;
#pragma unroll
  for (int it = 0; it < 4; ++it) {
    int n = tid + it * 256;
    if (n < NT_) {
      float e = __expf(sex[n] - mx);
      lsum += e;
      const bf16* vp = &P[(size_t)n * 384 + 128 + hd * 16];
      bf16x8 v0 = *(const bf16x8*)vp, v1 = *(const bf16x8*)(vp + 8);
#pragma unroll
      for (int i = 0; i < 8; ++i) { acc[i] += e * (float)v0[i]; acc[8 + i] += e * (float)v1[i]; }
    }
  }
#pragma unroll
  for (int o = 32; o > 0; o >>= 1) {
    lsum += __shfl_xor(lsum, o);
#pragma unroll
    for (int i = 0; i < 16; ++i) acc[i] += __shfl_xor(acc[i], o);
  }
  if ((tid & 63) == 0) {
    wacc[tid >> 6][16] = lsum;
#pragma unroll
    for (int i = 0; i < 16; ++i) wacc[tid >> 6][i] = acc[i];
  }
  __syncthreads();
  if (tid < 16) {
    float a = wacc[0][tid] + wacc[1][tid] + wacc[2][tid] + wacc[3][tid];
    float L = wacc[0][16] + wacc[1][16] + wacc[2][16] + wacc[3][16];
    glimpse[b * 128 + hd * 16 + tid] = a / L;
  }
}

__global__ void g2_kernel(const float* __restrict__ glimpse, const float* __restrict__ Wout,
                          float* __restrict__ g2) {
  __shared__ float sg[128];
  int b = blockIdx.x, d = threadIdx.x;
  sg[d] = glimpse[b * 128 + d];
  __syncthreads();
  float s = 0.f;
  for (int k = 0; k < 128; ++k) s += sg[k] * Wout[k * 128 + d];
  g2[b * 128 + d] = s;
}

__global__ __launch_bounds__(256) void logits_kernel(
    const bf16* __restrict__ proj, const float* __restrict__ g2,
    const int* __restrict__ mask, float* __restrict__ logits) {
  int b = blockIdx.y;
  int n = blockIdx.x * 256 + threadIdx.x;
  __shared__ float sg[128];
  if (threadIdx.x < 128) sg[threadIdx.x] = g2[b * 128 + threadIdx.x];
  __syncthreads();
  if (n >= NT_) return;
  const bf16* kp = &proj[((size_t)b * NT_ + n) * 384 + 256];
  float d = 0.f;
#pragma unroll
  for (int j = 0; j < 16; ++j) {
    bf16x8 v = *(const bf16x8*)&kp[j * 8];
#pragma unroll
    for (int i = 0; i < 8; ++i) d += sg[j * 8 + i] * (float)v[i];
  }
  d = 10.f * tanhf(d * 0.088388347648318447f);
  logits[b * NT_ + n] = mask[b * NT_ + n] ? NEGV : d;
}

__global__ __launch_bounds__(256) void lsm_kernel(const float* __restrict__ logits, float* __restrict__ out) {
  int b = blockIdx.x, tid = threadIdx.x;
  __shared__ float red[256];
  float mx = -1e30f;
  for (int n = tid; n < NT_; n += 256) mx = fmaxf(mx, logits[b * NT_ + n]);
  red[tid] = mx; __syncthreads();
  for (int s = 128; s > 0; s >>= 1) { if (tid < s) red[tid] = fmaxf(red[tid], red[tid + s]); __syncthreads(); }
  mx = red[0]; __syncthreads();
  float sm = 0.f;
  for (int n = tid; n < NT_; n += 256) sm += __expf(logits[b * NT_ + n] - mx);
  red[tid] = sm; __syncthreads();
  for (int s = 128; s > 0; s >>= 1) { if (tid < s) red[tid] += red[tid + s]; __syncthreads(); }
  float lse = mx + logf(red[0]);
  for (int n = tid; n < NT_; n += 256) out[(size_t)b * NT_ + n] = logits[b * NT_ + n] - lse;
}

// ---------------- launcher ----------------
extern "C" void kernel_launch(void* const* d_in, const int* in_sizes, int n_in,
                              void* d_out, int out_size, void* d_ws, size_t ws_size,
                              hipStream_t stream) {
  const float* depot        = (const float*)d_in[0];
  const float* loc          = (const float*)d_in[1];
  const float* demand       = (const float*)d_in[2];
  const int*   mask         = (const int*)d_in[3];
  const float* W_init_node  = (const float*)d_in[4];
  const float* b_init_node  = (const float*)d_in[5];
  const float* W_init_depot = (const float*)d_in[6];
  const float* b_init_depot = (const float*)d_in[7];
  const float* enc_Wqkv     = (const float*)d_in[8];
  const float* enc_Wo       = (const float*)d_in[9];
  const float* enc_W1       = (const float*)d_in[10];
  const float* enc_b1       = (const float*)d_in[11];
  const float* enc_W2       = (const float*)d_in[12];
  const float* enc_b2       = (const float*)d_in[13];
  const float* bn1_s        = (const float*)d_in[14];
  const float* bn1_b        = (const float*)d_in[15];
  const float* bn2_s        = (const float*)d_in[16];
  const float* bn2_b        = (const float*)d_in[17];
  const float* W_proj       = (const float*)d_in[18];
  const float* W_fixed      = (const float*)d_in[19];
  const float* W_step       = (const float*)d_in[20];
  const float* W_out        = (const float*)d_in[21];
  float* out = (float*)d_out;

  char* base = (char*)d_ws;
  bf16*  hb0   = (bf16*)(base);                        // 8,208,384
  bf16*  ab    = (bf16*)(base + 8208384);              // 8,208,384
  bf16*  Qh    = (bf16*)(base + 16416768);             // 8,388,608 [bh][NTP][16]
  bf16*  Kh    = (bf16*)(base + 24805376);             // 8,388,608
  bf16*  Vh    = (bf16*)(base + 33193984);             // 8,388,608 [bh*16+c16][NTP]
  bf16*  xb1   = Qh;                                   // alias (post-mattn lifetime)
  bf16*  xb2   = (bf16*)(base + 41582592);             // 8,208,384
  bf16*  projb = (bf16*)(base + 49790976);             // 24,625,152
  bf16*  wb    = (bf16*)(base + 74416128);             // 884,736
  float* ps    = (float*)(base + 75300864);            // 262,144 [128 col][512]
  float* pq    = (float*)(base + 75563008);            // 262,144
  float* mi1   = (float*)(base + 75825152);            // 1,024
  float* mi2   = (float*)(base + 75826176);            // 1,024
  float* qry   = (float*)(base + 75827200);            // 16,384
  float* glim  = (float*)(base + 75843584);            // 16,384
  float* g2    = (float*)(base + 75859968);            // 16,384
  float* gep   = ps;                                   // decoder reuse
  float* logit = pq;                                   // decoder reuse

  bf16* wt_qkv  = wb;
  bf16* wt_wo   = wb + SZ_QKV;
  bf16* wt_w1   = wb + SZ_QKV + SZ_WO;
  bf16* wt_w2   = wb + SZ_QKV + SZ_WO + SZ_W1;
  bf16* wt_proj = wb + SZ_QKV + SZ_WO + SZ_W1 + SZ_W2;

  prep_w<<<1728, 256, 0, stream>>>(enc_Wqkv, enc_Wo, enc_W1, enc_W2, W_proj, wb);
  init_kernel<<<(ROWS * D_ + 255) / 256, 256, 0, stream>>>(
      depot, loc, demand, W_init_node, b_init_node, W_init_depot, b_init_depot, hb0);

  for (int l = 0; l < 2; ++l) {
    const bf16* hin = (l == 0) ? hb0 : xb2;
    if (l == 0)
      mgemm_qkv<false><<<dim3(3, 501), 256, 0, stream>>>(hin, wt_qkv, nullptr, Qh, Kh, Vh);
    else
      mgemm_qkv<true><<<dim3(3, 501), 256, 0, stream>>>(hin, wt_qkv + (size_t)384 * 128, mi2, Qh, Kh, Vh);
    mattn<<<dim3(256, 8), 256, 0, stream>>>(Qh, Kh, Vh, ab);
    if (l == 0)
      mgemm<128, 128, false, false, true, true, false, false><<<dim3(1, 501), 256, 0, stream>>>(
          ab, wt_wo, nullptr, hin, xb1, ps, pq, nullptr, nullptr);
    else
      mgemm<128, 128, false, false, true, true, false, true><<<dim3(1, 501), 256, 0, stream>>>(
          ab, wt_wo + (size_t)128 * 128, nullptr, hin, xb1, ps, pq, nullptr, mi2);
    stats_final<<<1, 512, 0, stream>>>(ps, pq, bn1_s + l * D_, bn1_b + l * D_, mi1);
    fffused<<<501, 256, 0, stream>>>(
        xb1, mi1, wt_w1 + (size_t)l * 512 * 128, enc_b1 + (size_t)l * FF_,
        wt_w2 + (size_t)l * 128 * 512, enc_b2 + (size_t)l * D_, xb2, ps, pq);
    stats_final<<<1, 512, 0, stream>>>(ps, pq, bn2_s + l * D_, bn2_b + l * D_, mi2);
  }

  // decoder
  mgemm<384, 128, false, false, false, false, true, false><<<dim3(3, 501), 256, 0, stream>>>(
      xb2, wt_proj, nullptr, nullptr, projb, nullptr, nullptr, mi2, nullptr);
  ge_partial<<<dim3(32, 8), 128, 0, stream>>>(xb2, mi2, gep);
  query_kernel<<<32, 128, 0, stream>>>(gep, xb2, mi2, W_fixed, W_step, qry);
  glimpse_kernel<<<256, 256, 0, stream>>>(projb, qry, mask, glim);
  g2_kernel<<<32, 128, 0, stream>>>(glim, W_out, g2);
  logits_kernel<<<dim3(4, 32), 256, 0, stream>>>(projb, g2, mask, logit);
  lsm_kernel<<<32, 256, 0, stream>>>(logit, out);
}